// Round 7
// baseline (715.317 us; speedup 1.0000x reference)
//
#include <hip/hip_runtime.h>
#include <hip/hip_bf16.h>

typedef unsigned short u16;
typedef __bf16 bf16x8 __attribute__((ext_vector_type(8)));
typedef float f32x4 __attribute__((ext_vector_type(4)));
typedef unsigned short u16x8 __attribute__((ext_vector_type(8)));

__device__ __forceinline__ u16 f2bf(float f) {
  union { float f; unsigned u; } v; v.f = f;
  unsigned r = (v.u + 0x7FFFu + ((v.u >> 16) & 1u)) >> 16;
  return (u16)r;
}
__device__ __forceinline__ float bf2f(u16 s) {
  union { unsigned u; float f; } v; v.u = ((unsigned)s) << 16;
  return v.f;
}
__device__ __forceinline__ f32x4 zero4() { f32x4 z = {0.f, 0.f, 0.f, 0.f}; return z; }

__device__ __forceinline__ void async16(void* lds, const void* g) {
  __builtin_amdgcn_global_load_lds(
      (__attribute__((address_space(1))) void*)(void*)g,
      (__attribute__((address_space(3))) void*)lds, 16, 0, 0);
}

// ---------------------------------------------------------------------------
// Dtype sniff: 1 = f32 inputs, 0 = bf16 inputs. Deterministic.
// ---------------------------------------------------------------------------
__global__ void sniff_dtype(const unsigned* __restrict__ X, int* __restrict__ flag) {
  __shared__ int cnt;
  if (threadIdx.x == 0) cnt = 0;
  __syncthreads();
  unsigned w = X[(size_t)threadIdx.x * 16384 + 1000];
  int e = (int)((w >> 7) & 0xFF);
  if (e >= 100 && e <= 150) atomicAdd(&cnt, 1);
  __syncthreads();
  if (threadIdx.x == 0) flag[0] = (cnt < 192) ? 1 : 0;
}

// ---------------------------------------------------------------------------
// X ingest -> bf16.
// ---------------------------------------------------------------------------
__global__ __launch_bounds__(256) void convert_x(
    const void* __restrict__ X, u16* __restrict__ dst, const int* __restrict__ flag) {
  const int mode = flag[0];
  size_t i8 = ((size_t)blockIdx.x * 256 + threadIdx.x) * 8;
  if (mode) {
    const float4* f = (const float4*)X;
    float4 a = f[i8 / 4], b = f[i8 / 4 + 1];
    u16x8 o;
    o[0] = f2bf(a.x); o[1] = f2bf(a.y); o[2] = f2bf(a.z); o[3] = f2bf(a.w);
    o[4] = f2bf(b.x); o[5] = f2bf(b.y); o[6] = f2bf(b.z); o[7] = f2bf(b.w);
    *(u16x8*)&dst[i8] = o;
  } else {
    *(u16x8*)&dst[i8] = *(const u16x8*)&((const u16*)X)[i8];
  }
}

// ---------------------------------------------------------------------------
// Weight transpose + convert: Wt[n][k] = bf16(W[k][n]), 2048x2048.
// ---------------------------------------------------------------------------
__global__ __launch_bounds__(256) void transpose_w(
    const void* __restrict__ src, u16* __restrict__ d, const int* __restrict__ flag)
{
  __shared__ u16 t[64][65];
  const int mode = flag[0];
  int r0 = blockIdx.y * 64, c0 = blockIdx.x * 64;
  int tid = threadIdx.x;
  for (int j = 0; j < 2; ++j) {
    int idx = tid + j * 256;
    int r = idx >> 3, c = (idx & 7) * 8;
    size_t base = (size_t)(r0 + r) * 2048 + c0 + c;
    if (mode) {
      const float4* f = (const float4*)src;
      float4 a = f[base / 4], b = f[base / 4 + 1];
      t[r][c + 0] = f2bf(a.x); t[r][c + 1] = f2bf(a.y);
      t[r][c + 2] = f2bf(a.z); t[r][c + 3] = f2bf(a.w);
      t[r][c + 4] = f2bf(b.x); t[r][c + 5] = f2bf(b.y);
      t[r][c + 6] = f2bf(b.z); t[r][c + 7] = f2bf(b.w);
    } else {
      u16x8 v = *(const u16x8*)&((const u16*)src)[base];
      for (int q = 0; q < 8; ++q) t[r][c + q] = v[q];
    }
  }
  __syncthreads();
  for (int j = 0; j < 2; ++j) {
    int idx = tid + j * 256;
    int c = idx >> 3, r = (idx & 7) * 8;
    u16x8 v;
    for (int q = 0; q < 8; ++q) v[q] = t[r + q][c];
    *(u16x8*)&d[(size_t)(c0 + c) * 2048 + r0 + r] = v;
  }
}

// ---------------------------------------------------------------------------
// V transpose: Vt[(b*16+h)][d][kv] = V[b*2048+kv][h*128+d]
// ---------------------------------------------------------------------------
__global__ __launch_bounds__(256) void transpose_v(
    const u16* __restrict__ V, u16* __restrict__ Vt)
{
  __shared__ u16 t[64][65];
  int bh = blockIdx.z;
  int b = bh >> 4, h = bh & 15;
  int kv0 = blockIdx.x * 64, d0 = blockIdx.y * 64;
  int tid = threadIdx.x;
  for (int j = 0; j < 2; ++j) {
    int idx = tid + j * 256;
    int r = idx >> 3, c = (idx & 7) * 8;
    u16x8 v = *(const u16x8*)&V[(size_t)(b * 2048 + kv0 + r) * 2048 + h * 128 + d0 + c];
    for (int q = 0; q < 8; ++q) t[r][c + q] = v[q];
  }
  __syncthreads();
  for (int j = 0; j < 2; ++j) {
    int idx = tid + j * 256;
    int c = idx >> 3, r = (idx & 7) * 8;
    u16x8 v;
    for (int q = 0; q < 8; ++q) v[q] = t[r + q][c];
    *(u16x8*)&Vt[((size_t)bh * 128 + d0 + c) * 2048 + kv0 + r] = v;
  }
}

// ---------------------------------------------------------------------------
// RoPE in-place on Q and K (bf16). pos = token % 2048. Precise sincosf.
// ---------------------------------------------------------------------------
__global__ __launch_bounds__(256) void rope_k(u16* __restrict__ Qp, u16* __restrict__ Kp)
{
  int idx = blockIdx.x * 256 + threadIdx.x;
  u16* X = blockIdx.y ? Kp : Qp;
  int i8 = (idx & 7) * 8;
  int h = (idx >> 3) & 15;
  int tok = idx >> 7;
  int pos = tok & 2047;
  size_t base = (size_t)tok * 2048 + h * 128 + i8;
  u16x8 a = *(const u16x8*)&X[base];
  u16x8 bv = *(const u16x8*)&X[base + 64];
  u16x8 ra, rb;
  for (int j = 0; j < 8; ++j) {
    float fi = (float)(i8 + j);
    float invf = __expf(fi * -0.14391156831212787f);  // ln(10000)/64
    float th = (float)pos * invf;
    float c, s;
    sincosf(th, &s, &c);
    float x1 = bf2f(a[j]), x2 = bf2f(bv[j]);
    ra[j] = f2bf(x1 * c - x2 * s);
    rb[j] = f2bf(x2 * c + x1 * s);
  }
  *(u16x8*)&X[base] = ra;
  *(u16x8*)&X[base + 64] = rb;
}

// ---------------------------------------------------------------------------
// Shared 128x128 GEMM machinery (m97-structure + depth-1 compile-time dbuf).
// ---------------------------------------------------------------------------
__device__ __forceinline__ void qkv_stage(
    u16* As, u16* Bs, const u16* A, const u16* Bt,
    int m0, int n0full, int kt, int tid, const int* rowA, const int* gA)
{
  for (int j = 0; j < 2; ++j) {
    int tf = tid + j * 256;
    async16(&As[tf * 8], &A[(size_t)(m0 + rowA[j]) * 2048 + kt + gA[j] * 8]);
    async16(&Bs[tf * 8], &Bt[(size_t)(n0full + rowA[j]) * 2048 + kt + gA[j] * 8]);
  }
}

__device__ __forceinline__ void qkv_compute(
    const u16* As, const u16* Bs, f32x4 (&acc)[4][4],
    int wr, int wc, int quad, int l)
{
  bf16x8 af[4], bfr[4];
  for (int mt = 0; mt < 4; ++mt) {
    int row = wr * 64 + mt * 16 + l;
    int g = quad ^ ((row >> 1) & 3);
    af[mt] = *(const bf16x8*)&As[row * 32 + g * 8];
  }
  for (int nt = 0; nt < 4; ++nt) {
    int row = wc * 64 + nt * 16 + l;
    int g = quad ^ ((row >> 1) & 3);
    bfr[nt] = *(const bf16x8*)&Bs[row * 32 + g * 8];
  }
  for (int mt = 0; mt < 4; ++mt)
    for (int nt = 0; nt < 4; ++nt)
      acc[mt][nt] = __builtin_amdgcn_mfma_f32_16x16x32_bf16(af[mt], bfr[nt], acc[mt][nt], 0, 0, 0);
}

// ---------------------------------------------------------------------------
// Fused QKV GEMM — unchanged from round 6 (known-passing).
// ---------------------------------------------------------------------------
__global__ __launch_bounds__(256) void qkv_gemm(
    const u16* __restrict__ A, const u16* __restrict__ Bt,
    u16* __restrict__ Qw, u16* __restrict__ Kw, u16* __restrict__ Vw)
{
  __shared__ __align__(16) u16 As0[128 * 32];
  __shared__ __align__(16) u16 Bs0[128 * 32];
  __shared__ __align__(16) u16 As1[128 * 32];
  __shared__ __align__(16) u16 Bs1[128 * 32];
  const int K = 2048, N = 2048;
  const int tid = threadIdx.x;
  const int wave = tid >> 6, lane = tid & 63;
  const int quad = lane >> 4, l = lane & 15;
  const int wr = wave >> 1, wc = wave & 1;
  const int m0 = blockIdx.y * 128, n0full = blockIdx.x * 128;
  const int mat = n0full >> 11;
  const int n0 = n0full & 2047;
  u16* C = (mat == 0) ? Qw : ((mat == 1) ? Kw : Vw);

  f32x4 acc[4][4];
  for (int i = 0; i < 4; ++i)
    for (int j = 0; j < 4; ++j) acc[i][j] = zero4();

  int rowA[2], gA[2];
  for (int j = 0; j < 2; ++j) {
    int tf = tid + j * 256;
    rowA[j] = tf >> 2;
    gA[j] = (tf & 3) ^ ((rowA[j] >> 1) & 3);
  }

  qkv_stage(As0, Bs0, A, Bt, m0, n0full, 0, tid, rowA, gA);
  __syncthreads();  // drain + visibility of buf0

  for (int kt = 0; kt < K; kt += 64) {
    qkv_stage(As1, Bs1, A, Bt, m0, n0full, kt + 32, tid, rowA, gA);
    qkv_compute(As0, Bs0, acc, wr, wc, quad, l);
    __syncthreads();  // drains buf1 loads (flew during compute) + WAR for buf0
    if (kt + 64 < K)
      qkv_stage(As0, Bs0, A, Bt, m0, n0full, kt + 64, tid, rowA, gA);
    qkv_compute(As1, Bs1, acc, wr, wc, quad, l);
    __syncthreads();
  }

  for (int mt = 0; mt < 4; ++mt)
    for (int nt = 0; nt < 4; ++nt)
      for (int r = 0; r < 4; ++r) {
        int m = m0 + wr * 64 + mt * 16 + quad * 4 + r;
        int n = n0 + wc * 64 + nt * 16 + l;
        C[(size_t)m * N + n] = f2bf(acc[mt][nt][r]);
      }
}

// ---------------------------------------------------------------------------
// Wo GEMM — ROUND-14 DELTA: 64x64 tile REPLACED by the 128x128 m97-structure
//   (identical to qkv_gemm) + dual-mode epilogue.
//   Rationale: budget reconstruction puts the old 64x64 kernel at ~100 µs
//   (ladder: 64^2 = 343 TF vs 128^2 = 912, m92/m103). Same FLOPs at qkv's
//   measured 775 TF = ~44 µs. Grid (2048/128, 4096/128) = (16,32) = 512
//   blocks = 2/CU. LDS 32 KB. Known-good numerics, new epilogue only.
// ---------------------------------------------------------------------------
__global__ __launch_bounds__(256) void gemm128_bt(
    const u16* __restrict__ A, const u16* __restrict__ Bt, void* __restrict__ C,
    int M, int N, int K, const int* __restrict__ flag, int dual)
{
  __shared__ __align__(16) u16 As0[128 * 32];
  __shared__ __align__(16) u16 Bs0[128 * 32];
  __shared__ __align__(16) u16 As1[128 * 32];
  __shared__ __align__(16) u16 Bs1[128 * 32];
  const int mode = dual ? flag[0] : 0;
  const int tid = threadIdx.x;
  const int wave = tid >> 6, lane = tid & 63;
  const int quad = lane >> 4, l = lane & 15;
  const int wr = wave >> 1, wc = wave & 1;
  const int m0 = blockIdx.y * 128, n0 = blockIdx.x * 128;

  f32x4 acc[4][4];
  for (int i = 0; i < 4; ++i)
    for (int j = 0; j < 4; ++j) acc[i][j] = zero4();

  int rowA[2], gA[2];
  for (int j = 0; j < 2; ++j) {
    int tf = tid + j * 256;
    rowA[j] = tf >> 2;
    gA[j] = (tf & 3) ^ ((rowA[j] >> 1) & 3);
  }

  qkv_stage(As0, Bs0, A, Bt, m0, n0, 0, tid, rowA, gA);
  __syncthreads();

  for (int kt = 0; kt < K; kt += 64) {
    qkv_stage(As1, Bs1, A, Bt, m0, n0, kt + 32, tid, rowA, gA);
    qkv_compute(As0, Bs0, acc, wr, wc, quad, l);
    __syncthreads();
    if (kt + 64 < K)
      qkv_stage(As0, Bs0, A, Bt, m0, n0, kt + 64, tid, rowA, gA);
    qkv_compute(As1, Bs1, acc, wr, wc, quad, l);
    __syncthreads();
  }

  for (int mt = 0; mt < 4; ++mt)
    for (int nt = 0; nt < 4; ++nt)
      for (int r = 0; r < 4; ++r) {
        int m = m0 + wr * 64 + mt * 16 + quad * 4 + r;
        int n = n0 + wc * 64 + nt * 16 + l;
        if (mode) ((float*)C)[(size_t)m * N + n] = acc[mt][nt][r];
        else      ((u16*)C)[(size_t)m * N + n] = f2bf(acc[mt][nt][r]);
      }
}

// ---------------------------------------------------------------------------
// Flash attention, causal — unchanged from round 6 (causal-paired balanced
// grid + depth-1 compile-time dbuf pipeline).
// ---------------------------------------------------------------------------
__device__ __forceinline__ void fl_stage(
    u16* Ks, u16* Vs, const u16* K, const u16* Vt,
    size_t kbase, size_t vbase, int kt, int tid)
{
  for (int j = 0; j < 4; ++j) {
    int tf = tid + j * 256;
    int row = tf >> 4, p = tf & 15;
    int g = p ^ (row & 7);
    async16(&Ks[tf * 8], &K[kbase + (size_t)(kt * 64 + row) * 2048 + g * 8]);
  }
  for (int j = 0; j < 4; ++j) {
    int tf = tid + j * 256;
    int row = tf >> 3, p = tf & 7;
    int g = p ^ (row & 7);
    async16(&Vs[tf * 8], &Vt[vbase + (size_t)row * 2048 + kt * 64 + g * 8]);
  }
}

__global__ __launch_bounds__(256) void flash_k(
    const u16* __restrict__ Q, const u16* __restrict__ K,
    const u16* __restrict__ Vt, u16* __restrict__ O)
{
  __shared__ __align__(16) u16 Ks0[64 * 128];
  __shared__ __align__(16) u16 Vs0[128 * 64];
  __shared__ __align__(16) u16 Ks1[64 * 128];
  __shared__ __align__(16) u16 Vs1[128 * 64];
  __shared__ __align__(16) u16 Ps[4][16 * 64];

  const int tid = threadIdx.x;
  const int wave = tid >> 6, lane = tid & 63;
  const int quad = lane >> 4, l = lane & 15;
  const int pair = blockIdx.x;            // 0..15
  const int h = blockIdx.y, b = blockIdx.z;

  const size_t kbase = ((size_t)b * 2048) * 2048 + h * 128;
  const size_t vbase = ((size_t)(b * 16 + h)) * 128 * 2048;

  for (int half = 0; half < 2; ++half) {
    const int qt = half ? pair : (31 - pair);  // big tile first

    const size_t qoff = ((size_t)(b * 2048 + qt * 64)) * 2048 + h * 128;
    bf16x8 qf[4];
    for (int ks = 0; ks < 4; ++ks)
      qf[ks] = *(const bf16x8*)&Q[qoff + (size_t)(wave * 16 + l) * 2048 + (ks * 4 + quad) * 8];

    f32x4 Oacc[8];
    for (int i = 0; i < 8; ++i) Oacc[i] = zero4();
    float mi[4] = {-3e38f, -3e38f, -3e38f, -3e38f};
    float li[4] = {0.f, 0.f, 0.f, 0.f};

    auto fl_body = [&](const u16* Ksb, const u16* Vsb, int kt) {
      f32x4 S[4];
      for (int nt = 0; nt < 4; ++nt) S[nt] = zero4();
      for (int ks = 0; ks < 4; ++ks) {
        int g = ks * 4 + quad;
        for (int nt = 0; nt < 4; ++nt) {
          bf16x8 bk = *(const bf16x8*)&Ksb[(nt * 16 + l) * 128 + (g ^ (l & 7)) * 8];
          S[nt] = __builtin_amdgcn_mfma_f32_16x16x32_bf16(qf[ks], bk, S[nt], 0, 0, 0);
        }
      }

      const bool dg = (kt == qt);
      float Pv[4][4];
      float rm[4] = {-3e38f, -3e38f, -3e38f, -3e38f};
      for (int nt = 0; nt < 4; ++nt)
        for (int r = 0; r < 4; ++r) {
          float s = S[nt][r] * 0.08838834764831845f;  // 1/sqrt(128)
          if (dg && (nt * 16 + l > wave * 16 + quad * 4 + r)) s = -3e38f;
          Pv[nt][r] = s;
          rm[r] = fmaxf(rm[r], s);
        }
      for (int r = 0; r < 4; ++r)
        for (int off = 1; off < 16; off <<= 1)
          rm[r] = fmaxf(rm[r], __shfl_xor(rm[r], off));
      float al[4], rs[4];
      for (int r = 0; r < 4; ++r) {
        float mn = fmaxf(mi[r], rm[r]);
        al[r] = __expf(mi[r] - mn);
        mi[r] = mn;
        rs[r] = 0.f;
      }
      for (int nt = 0; nt < 4; ++nt)
        for (int r = 0; r < 4; ++r) {
          float p = __expf(Pv[nt][r] - mi[r]);
          Pv[nt][r] = p;
          rs[r] += p;
        }
      for (int r = 0; r < 4; ++r) {
        for (int off = 1; off < 16; off <<= 1)
          rs[r] += __shfl_xor(rs[r], off);
        li[r] = li[r] * al[r] + rs[r];
      }
      for (int nt = 0; nt < 4; ++nt) {
        int gc = nt * 2 + (l >> 3);
        for (int r = 0; r < 4; ++r) {
          int row = quad * 4 + r;
          Ps[wave][row * 64 + ((gc ^ (row & 7)) * 8) + (l & 7)] = f2bf(Pv[nt][r]);
        }
      }
      for (int d = 0; d < 8; ++d)
        for (int r = 0; r < 4; ++r) Oacc[d][r] *= al[r];
      for (int ks = 0; ks < 2; ++ks) {
        int g = ks * 4 + quad;
        bf16x8 ap = *(const bf16x8*)&Ps[wave][l * 64 + (g ^ (l & 7)) * 8];
        for (int d = 0; d < 8; ++d) {
          bf16x8 bv = *(const bf16x8*)&Vsb[(d * 16 + l) * 64 + (g ^ (l & 7)) * 8];
          Oacc[d] = __builtin_amdgcn_mfma_f32_16x16x32_bf16(ap, bv, Oacc[d], 0, 0, 0);
        }
      }
    };

    // prologue: stage kt=0 into buf0 (prev half's end barrier guards WAR)
    fl_stage(Ks0, Vs0, K, Vt, kbase, vbase, 0, tid);
    __syncthreads();

    for (int kt = 0; kt <= qt; kt += 2) {
      if (kt + 1 <= qt) fl_stage(Ks1, Vs1, K, Vt, kbase, vbase, kt + 1, tid);
      fl_body(Ks0, Vs0, kt);
      __syncthreads();
      if (kt + 1 <= qt) {
        if (kt + 2 <= qt) fl_stage(Ks0, Vs0, K, Vt, kbase, vbase, kt + 2, tid);
        fl_body(Ks1, Vs1, kt + 1);
        __syncthreads();
      }
    }

    float inv[4];
    for (int r = 0; r < 4; ++r) inv[r] = 1.f / li[r];
    size_t obase = ((size_t)(b * 2048 + qt * 64 + wave * 16)) * 2048 + h * 128;
    for (int d = 0; d < 8; ++d)
      for (int r = 0; r < 4; ++r)
        O[obase + (size_t)(quad * 4 + r) * 2048 + d * 16 + l] = f2bf(Oacc[d][r] * inv[r]);
  }
}

// ---------------------------------------------------------------------------
extern "C" void kernel_launch(void* const* d_in, const int* in_sizes, int n_in,
                              void* d_out, int out_size, void* d_ws, size_t ws_size,
                              hipStream_t stream) {
  const void* X  = d_in[0];
  const void* Wq = d_in[3];
  const void* Wk = d_in[4];
  const void* Wv = d_in[5];
  const void* Wo = d_in[6];

  u16* base = (u16*)d_ws;
  int* flag = (int*)d_ws;
  const size_t TOK = 4096, DM = 2048;
  u16* Xbf = base + 128;               // 8M u16
  u16* Qw  = Xbf + TOK * DM;           // 8M
  u16* Kw  = Qw + TOK * DM;            // 8M
  u16* Vw  = Kw + TOK * DM;            // 8M (V, then attention output)
  u16* WT3 = Vw + TOK * DM;            // 12M u16: WqT ++ WkT ++ WvT (6144x2048)
  u16* Vtw = Xbf;                      // X dead after QKV gemm

  sniff_dtype<<<1, 256, 0, stream>>>((const unsigned*)X, flag);
  convert_x<<<4096, 256, 0, stream>>>(X, Xbf, flag);

  transpose_w<<<dim3(32, 32), 256, 0, stream>>>(Wq, WT3, flag);
  transpose_w<<<dim3(32, 32), 256, 0, stream>>>(Wk, WT3 + DM * DM, flag);
  transpose_w<<<dim3(32, 32), 256, 0, stream>>>(Wv, WT3 + 2 * DM * DM, flag);
  qkv_gemm<<<dim3(48, 32), 256, 0, stream>>>(Xbf, WT3, Qw, Kw, Vw);

  rope_k<<<dim3(2048, 2), 256, 0, stream>>>(Qw, Kw);
  transpose_v<<<dim3(32, 2, 32), 256, 0, stream>>>(Vw, Vtw);
  flash_k<<<dim3(16, 16, 2), 256, 0, stream>>>(Qw, Kw, Vtw, Vw);

  transpose_w<<<dim3(32, 32), 256, 0, stream>>>(Wo, WT3, flag);
  gemm128_bt<<<dim3(16, 32), 256, 0, stream>>>(Vw, WT3, d_out, 4096, 2048, 2048, flag, 1);
}

// Round 8
// 477.116 us; speedup vs baseline: 1.4993x; 1.4993x over previous
//
#include <hip/hip_runtime.h>
#include <hip/hip_bf16.h>

typedef unsigned short u16;
typedef __bf16 bf16x8 __attribute__((ext_vector_type(8)));
typedef float f32x4 __attribute__((ext_vector_type(4)));
typedef unsigned short u16x8 __attribute__((ext_vector_type(8)));

__device__ __forceinline__ u16 f2bf(float f) {
  union { float f; unsigned u; } v; v.f = f;
  unsigned r = (v.u + 0x7FFFu + ((v.u >> 16) & 1u)) >> 16;
  return (u16)r;
}
__device__ __forceinline__ float bf2f(u16 s) {
  union { unsigned u; float f; } v; v.u = ((unsigned)s) << 16;
  return v.f;
}
__device__ __forceinline__ f32x4 zero4() { f32x4 z = {0.f, 0.f, 0.f, 0.f}; return z; }

__device__ __forceinline__ void async16(void* lds, const void* g) {
  __builtin_amdgcn_global_load_lds(
      (__attribute__((address_space(1))) void*)(void*)g,
      (__attribute__((address_space(3))) void*)lds, 16, 0, 0);
}

// ---------------------------------------------------------------------------
// Dtype sniff: 1 = f32 inputs, 0 = bf16 inputs. Deterministic.
// ---------------------------------------------------------------------------
__global__ void sniff_dtype(const unsigned* __restrict__ X, int* __restrict__ flag) {
  __shared__ int cnt;
  if (threadIdx.x == 0) cnt = 0;
  __syncthreads();
  unsigned w = X[(size_t)threadIdx.x * 16384 + 1000];
  int e = (int)((w >> 7) & 0xFF);
  if (e >= 100 && e <= 150) atomicAdd(&cnt, 1);
  __syncthreads();
  if (threadIdx.x == 0) flag[0] = (cnt < 192) ? 1 : 0;
}

// ---------------------------------------------------------------------------
// X ingest -> bf16.
// ---------------------------------------------------------------------------
__global__ __launch_bounds__(256) void convert_x(
    const void* __restrict__ X, u16* __restrict__ dst, const int* __restrict__ flag) {
  const int mode = flag[0];
  size_t i8 = ((size_t)blockIdx.x * 256 + threadIdx.x) * 8;
  if (mode) {
    const float4* f = (const float4*)X;
    float4 a = f[i8 / 4], b = f[i8 / 4 + 1];
    u16x8 o;
    o[0] = f2bf(a.x); o[1] = f2bf(a.y); o[2] = f2bf(a.z); o[3] = f2bf(a.w);
    o[4] = f2bf(b.x); o[5] = f2bf(b.y); o[6] = f2bf(b.z); o[7] = f2bf(b.w);
    *(u16x8*)&dst[i8] = o;
  } else {
    *(u16x8*)&dst[i8] = *(const u16x8*)&((const u16*)X)[i8];
  }
}

// ---------------------------------------------------------------------------
// Weight transpose + convert: Wt[n][k] = bf16(W[k][n]), 2048x2048.
// ---------------------------------------------------------------------------
__global__ __launch_bounds__(256) void transpose_w(
    const void* __restrict__ src, u16* __restrict__ d, const int* __restrict__ flag)
{
  __shared__ u16 t[64][65];
  const int mode = flag[0];
  int r0 = blockIdx.y * 64, c0 = blockIdx.x * 64;
  int tid = threadIdx.x;
  for (int j = 0; j < 2; ++j) {
    int idx = tid + j * 256;
    int r = idx >> 3, c = (idx & 7) * 8;
    size_t base = (size_t)(r0 + r) * 2048 + c0 + c;
    if (mode) {
      const float4* f = (const float4*)src;
      float4 a = f[base / 4], b = f[base / 4 + 1];
      t[r][c + 0] = f2bf(a.x); t[r][c + 1] = f2bf(a.y);
      t[r][c + 2] = f2bf(a.z); t[r][c + 3] = f2bf(a.w);
      t[r][c + 4] = f2bf(b.x); t[r][c + 5] = f2bf(b.y);
      t[r][c + 6] = f2bf(b.z); t[r][c + 7] = f2bf(b.w);
    } else {
      u16x8 v = *(const u16x8*)&((const u16*)src)[base];
      for (int q = 0; q < 8; ++q) t[r][c + q] = v[q];
    }
  }
  __syncthreads();
  for (int j = 0; j < 2; ++j) {
    int idx = tid + j * 256;
    int c = idx >> 3, r = (idx & 7) * 8;
    u16x8 v;
    for (int q = 0; q < 8; ++q) v[q] = t[r + q][c];
    *(u16x8*)&d[(size_t)(c0 + c) * 2048 + r0 + r] = v;
  }
}

// ---------------------------------------------------------------------------
// V transpose: Vt[(b*16+h)][d][kv] = V[b*2048+kv][h*128+d]
// ---------------------------------------------------------------------------
__global__ __launch_bounds__(256) void transpose_v(
    const u16* __restrict__ V, u16* __restrict__ Vt)
{
  __shared__ u16 t[64][65];
  int bh = blockIdx.z;
  int b = bh >> 4, h = bh & 15;
  int kv0 = blockIdx.x * 64, d0 = blockIdx.y * 64;
  int tid = threadIdx.x;
  for (int j = 0; j < 2; ++j) {
    int idx = tid + j * 256;
    int r = idx >> 3, c = (idx & 7) * 8;
    u16x8 v = *(const u16x8*)&V[(size_t)(b * 2048 + kv0 + r) * 2048 + h * 128 + d0 + c];
    for (int q = 0; q < 8; ++q) t[r][c + q] = v[q];
  }
  __syncthreads();
  for (int j = 0; j < 2; ++j) {
    int idx = tid + j * 256;
    int c = idx >> 3, r = (idx & 7) * 8;
    u16x8 v;
    for (int q = 0; q < 8; ++q) v[q] = t[r + q][c];
    *(u16x8*)&Vt[((size_t)bh * 128 + d0 + c) * 2048 + kv0 + r] = v;
  }
}

// ---------------------------------------------------------------------------
// RoPE in-place on Q and K (bf16) — ROUND-15 DELTA: trig reuse across heads.
//   Old: one thread per (tok, h, i8) -> 8 sincosf each; the trig depends
//   only on (pos, i8+j), so 16 heads recomputed it 16x.
//   New: one thread per (tok, i8-slot, head-quad) handling 4 heads with ONE
//   set of 8 sincos (4x less trig, bit-identical values). Grid (512, 2).
// ---------------------------------------------------------------------------
__global__ __launch_bounds__(256) void rope_k(u16* __restrict__ Qp, u16* __restrict__ Kp)
{
  int idx = blockIdx.x * 256 + threadIdx.x;   // [0, 131072)
  u16* X = blockIdx.y ? Kp : Qp;
  int i8 = (idx & 7) * 8;                     // 8 slots of 8 within half-dh 64
  int hq = (idx >> 3) & 3;                    // head quad 0..3
  int tok = idx >> 5;                         // 0..4095
  int pos = tok & 2047;

  float c8[8], s8[8];
  for (int j = 0; j < 8; ++j) {
    float fi = (float)(i8 + j);
    float invf = __expf(fi * -0.14391156831212787f);  // ln(10000)/64
    float th = (float)pos * invf;
    sincosf(th, &s8[j], &c8[j]);
  }

  for (int hh = 0; hh < 4; ++hh) {
    int h = hq * 4 + hh;
    size_t base = (size_t)tok * 2048 + h * 128 + i8;
    u16x8 a = *(const u16x8*)&X[base];
    u16x8 bv = *(const u16x8*)&X[base + 64];
    u16x8 ra, rb;
    for (int j = 0; j < 8; ++j) {
      float x1 = bf2f(a[j]), x2 = bf2f(bv[j]);
      ra[j] = f2bf(x1 * c8[j] - x2 * s8[j]);
      rb[j] = f2bf(x2 * c8[j] + x1 * s8[j]);
    }
    *(u16x8*)&X[base] = ra;
    *(u16x8*)&X[base + 64] = rb;
  }
}

// ---------------------------------------------------------------------------
// Shared 128x128 GEMM machinery (m97-structure + depth-1 compile-time dbuf).
// ---------------------------------------------------------------------------
__device__ __forceinline__ void qkv_stage(
    u16* As, u16* Bs, const u16* A, const u16* Bt,
    int m0, int n0full, int kt, int tid, const int* rowA, const int* gA)
{
  for (int j = 0; j < 2; ++j) {
    int tf = tid + j * 256;
    async16(&As[tf * 8], &A[(size_t)(m0 + rowA[j]) * 2048 + kt + gA[j] * 8]);
    async16(&Bs[tf * 8], &Bt[(size_t)(n0full + rowA[j]) * 2048 + kt + gA[j] * 8]);
  }
}

__device__ __forceinline__ void qkv_compute(
    const u16* As, const u16* Bs, f32x4 (&acc)[4][4],
    int wr, int wc, int quad, int l)
{
  bf16x8 af[4], bfr[4];
  for (int mt = 0; mt < 4; ++mt) {
    int row = wr * 64 + mt * 16 + l;
    int g = quad ^ ((row >> 1) & 3);
    af[mt] = *(const bf16x8*)&As[row * 32 + g * 8];
  }
  for (int nt = 0; nt < 4; ++nt) {
    int row = wc * 64 + nt * 16 + l;
    int g = quad ^ ((row >> 1) & 3);
    bfr[nt] = *(const bf16x8*)&Bs[row * 32 + g * 8];
  }
  for (int mt = 0; mt < 4; ++mt)
    for (int nt = 0; nt < 4; ++nt)
      acc[mt][nt] = __builtin_amdgcn_mfma_f32_16x16x32_bf16(af[mt], bfr[nt], acc[mt][nt], 0, 0, 0);
}

// ---------------------------------------------------------------------------
// Fused QKV GEMM — unchanged (known-passing, 133 µs / 775 TF).
// ---------------------------------------------------------------------------
__global__ __launch_bounds__(256) void qkv_gemm(
    const u16* __restrict__ A, const u16* __restrict__ Bt,
    u16* __restrict__ Qw, u16* __restrict__ Kw, u16* __restrict__ Vw)
{
  __shared__ __align__(16) u16 As0[128 * 32];
  __shared__ __align__(16) u16 Bs0[128 * 32];
  __shared__ __align__(16) u16 As1[128 * 32];
  __shared__ __align__(16) u16 Bs1[128 * 32];
  const int K = 2048, N = 2048;
  const int tid = threadIdx.x;
  const int wave = tid >> 6, lane = tid & 63;
  const int quad = lane >> 4, l = lane & 15;
  const int wr = wave >> 1, wc = wave & 1;
  const int m0 = blockIdx.y * 128, n0full = blockIdx.x * 128;
  const int mat = n0full >> 11;
  const int n0 = n0full & 2047;
  u16* C = (mat == 0) ? Qw : ((mat == 1) ? Kw : Vw);

  f32x4 acc[4][4];
  for (int i = 0; i < 4; ++i)
    for (int j = 0; j < 4; ++j) acc[i][j] = zero4();

  int rowA[2], gA[2];
  for (int j = 0; j < 2; ++j) {
    int tf = tid + j * 256;
    rowA[j] = tf >> 2;
    gA[j] = (tf & 3) ^ ((rowA[j] >> 1) & 3);
  }

  qkv_stage(As0, Bs0, A, Bt, m0, n0full, 0, tid, rowA, gA);
  __syncthreads();  // drain + visibility of buf0

  for (int kt = 0; kt < K; kt += 64) {
    qkv_stage(As1, Bs1, A, Bt, m0, n0full, kt + 32, tid, rowA, gA);
    qkv_compute(As0, Bs0, acc, wr, wc, quad, l);
    __syncthreads();  // drains buf1 loads (flew during compute) + WAR for buf0
    if (kt + 64 < K)
      qkv_stage(As0, Bs0, A, Bt, m0, n0full, kt + 64, tid, rowA, gA);
    qkv_compute(As1, Bs1, acc, wr, wc, quad, l);
    __syncthreads();
  }

  for (int mt = 0; mt < 4; ++mt)
    for (int nt = 0; nt < 4; ++nt)
      for (int r = 0; r < 4; ++r) {
        int m = m0 + wr * 64 + mt * 16 + quad * 4 + r;
        int n = n0 + wc * 64 + nt * 16 + l;
        C[(size_t)m * N + n] = f2bf(acc[mt][nt][r]);
      }
}

// ---------------------------------------------------------------------------
// Wo GEMM — ROUND-15: REVERTED to round-6 gemm64_bt verbatim.
//   Round-7's 128x128 version hit a 55x HBM write amplification on d_out
//   (WRITE_SIZE 1.85 GB vs 33.5 MB logical; 308 µs at 79% HBM peak) —
//   mechanism unresolved; the 64x64 kernel provably never showed it.
// ---------------------------------------------------------------------------
__device__ __forceinline__ void g64_compute(
    const u16* As, const u16* Bs, f32x4 (&acc)[2][2],
    int wr, int wc, int quad, int l)
{
  bf16x8 af[2], bfr[2];
  for (int mt = 0; mt < 2; ++mt) {
    int row = wr * 32 + mt * 16 + l;
    int g = quad ^ ((row >> 1) & 3);
    af[mt] = *(const bf16x8*)&As[row * 32 + g * 8];
  }
  for (int nt = 0; nt < 2; ++nt) {
    int row = wc * 32 + nt * 16 + l;
    int g = quad ^ ((row >> 1) & 3);
    bfr[nt] = *(const bf16x8*)&Bs[row * 32 + g * 8];
  }
  for (int mt = 0; mt < 2; ++mt)
    for (int nt = 0; nt < 2; ++nt)
      acc[mt][nt] = __builtin_amdgcn_mfma_f32_16x16x32_bf16(af[mt], bfr[nt], acc[mt][nt], 0, 0, 0);
}

__global__ __launch_bounds__(256) void gemm64_bt(
    const u16* __restrict__ A, const u16* __restrict__ Bt, void* __restrict__ C,
    int M, int N, int K, const int* __restrict__ flag, int dual)
{
  __shared__ __align__(16) u16 As0[64 * 32];
  __shared__ __align__(16) u16 Bs0[64 * 32];
  __shared__ __align__(16) u16 As1[64 * 32];
  __shared__ __align__(16) u16 Bs1[64 * 32];
  const int mode = dual ? flag[0] : 0;
  const int tid = threadIdx.x;
  const int wave = tid >> 6, lane = tid & 63;
  const int quad = lane >> 4, l = lane & 15;
  const int wr = wave >> 1, wc = wave & 1;
  const int m0 = blockIdx.y * 64, n0 = blockIdx.x * 64;

  f32x4 acc[2][2];
  for (int i = 0; i < 2; ++i)
    for (int j = 0; j < 2; ++j) acc[i][j] = zero4();

  const int rowA = tid >> 2;
  const int gA = (tid & 3) ^ ((rowA >> 1) & 3);

  async16(&As0[tid * 8], &A[(size_t)(m0 + rowA) * K + gA * 8]);
  async16(&Bs0[tid * 8], &Bt[(size_t)(n0 + rowA) * K + gA * 8]);
  __syncthreads();

  for (int kt = 0; kt < K; kt += 64) {
    async16(&As1[tid * 8], &A[(size_t)(m0 + rowA) * K + kt + 32 + gA * 8]);
    async16(&Bs1[tid * 8], &Bt[(size_t)(n0 + rowA) * K + kt + 32 + gA * 8]);
    g64_compute(As0, Bs0, acc, wr, wc, quad, l);
    __syncthreads();
    if (kt + 64 < K) {
      async16(&As0[tid * 8], &A[(size_t)(m0 + rowA) * K + kt + 64 + gA * 8]);
      async16(&Bs0[tid * 8], &Bt[(size_t)(n0 + rowA) * K + kt + 64 + gA * 8]);
    }
    g64_compute(As1, Bs1, acc, wr, wc, quad, l);
    __syncthreads();
  }

  for (int mt = 0; mt < 2; ++mt)
    for (int nt = 0; nt < 2; ++nt)
      for (int r = 0; r < 4; ++r) {
        int m = m0 + wr * 32 + mt * 16 + quad * 4 + r;
        int n = n0 + wc * 32 + nt * 16 + l;
        if (mode) ((float*)C)[(size_t)m * N + n] = acc[mt][nt][r];
        else      ((u16*)C)[(size_t)m * N + n] = f2bf(acc[mt][nt][r]);
      }
}

// ---------------------------------------------------------------------------
// Flash attention, causal — unchanged (causal-paired balanced grid +
// depth-1 compile-time dbuf pipeline).
// ---------------------------------------------------------------------------
__device__ __forceinline__ void fl_stage(
    u16* Ks, u16* Vs, const u16* K, const u16* Vt,
    size_t kbase, size_t vbase, int kt, int tid)
{
  for (int j = 0; j < 4; ++j) {
    int tf = tid + j * 256;
    int row = tf >> 4, p = tf & 15;
    int g = p ^ (row & 7);
    async16(&Ks[tf * 8], &K[kbase + (size_t)(kt * 64 + row) * 2048 + g * 8]);
  }
  for (int j = 0; j < 4; ++j) {
    int tf = tid + j * 256;
    int row = tf >> 3, p = tf & 7;
    int g = p ^ (row & 7);
    async16(&Vs[tf * 8], &Vt[vbase + (size_t)row * 2048 + kt * 64 + g * 8]);
  }
}

__global__ __launch_bounds__(256) void flash_k(
    const u16* __restrict__ Q, const u16* __restrict__ K,
    const u16* __restrict__ Vt, u16* __restrict__ O)
{
  __shared__ __align__(16) u16 Ks0[64 * 128];
  __shared__ __align__(16) u16 Vs0[128 * 64];
  __shared__ __align__(16) u16 Ks1[64 * 128];
  __shared__ __align__(16) u16 Vs1[128 * 64];
  __shared__ __align__(16) u16 Ps[4][16 * 64];

  const int tid = threadIdx.x;
  const int wave = tid >> 6, lane = tid & 63;
  const int quad = lane >> 4, l = lane & 15;
  const int pair = blockIdx.x;            // 0..15
  const int h = blockIdx.y, b = blockIdx.z;

  const size_t kbase = ((size_t)b * 2048) * 2048 + h * 128;
  const size_t vbase = ((size_t)(b * 16 + h)) * 128 * 2048;

  for (int half = 0; half < 2; ++half) {
    const int qt = half ? pair : (31 - pair);  // big tile first

    const size_t qoff = ((size_t)(b * 2048 + qt * 64)) * 2048 + h * 128;
    bf16x8 qf[4];
    for (int ks = 0; ks < 4; ++ks)
      qf[ks] = *(const bf16x8*)&Q[qoff + (size_t)(wave * 16 + l) * 2048 + (ks * 4 + quad) * 8];

    f32x4 Oacc[8];
    for (int i = 0; i < 8; ++i) Oacc[i] = zero4();
    float mi[4] = {-3e38f, -3e38f, -3e38f, -3e38f};
    float li[4] = {0.f, 0.f, 0.f, 0.f};

    auto fl_body = [&](const u16* Ksb, const u16* Vsb, int kt) {
      f32x4 S[4];
      for (int nt = 0; nt < 4; ++nt) S[nt] = zero4();
      for (int ks = 0; ks < 4; ++ks) {
        int g = ks * 4 + quad;
        for (int nt = 0; nt < 4; ++nt) {
          bf16x8 bk = *(const bf16x8*)&Ksb[(nt * 16 + l) * 128 + (g ^ (l & 7)) * 8];
          S[nt] = __builtin_amdgcn_mfma_f32_16x16x32_bf16(qf[ks], bk, S[nt], 0, 0, 0);
        }
      }

      const bool dg = (kt == qt);
      float Pv[4][4];
      float rm[4] = {-3e38f, -3e38f, -3e38f, -3e38f};
      for (int nt = 0; nt < 4; ++nt)
        for (int r = 0; r < 4; ++r) {
          float s = S[nt][r] * 0.08838834764831845f;  // 1/sqrt(128)
          if (dg && (nt * 16 + l > wave * 16 + quad * 4 + r)) s = -3e38f;
          Pv[nt][r] = s;
          rm[r] = fmaxf(rm[r], s);
        }
      for (int r = 0; r < 4; ++r)
        for (int off = 1; off < 16; off <<= 1)
          rm[r] = fmaxf(rm[r], __shfl_xor(rm[r], off));
      float al[4], rs[4];
      for (int r = 0; r < 4; ++r) {
        float mn = fmaxf(mi[r], rm[r]);
        al[r] = __expf(mi[r] - mn);
        mi[r] = mn;
        rs[r] = 0.f;
      }
      for (int nt = 0; nt < 4; ++nt)
        for (int r = 0; r < 4; ++r) {
          float p = __expf(Pv[nt][r] - mi[r]);
          Pv[nt][r] = p;
          rs[r] += p;
        }
      for (int r = 0; r < 4; ++r) {
        for (int off = 1; off < 16; off <<= 1)
          rs[r] += __shfl_xor(rs[r], off);
        li[r] = li[r] * al[r] + rs[r];
      }
      for (int nt = 0; nt < 4; ++nt) {
        int gc = nt * 2 + (l >> 3);
        for (int r = 0; r < 4; ++r) {
          int row = quad * 4 + r;
          Ps[wave][row * 64 + ((gc ^ (row & 7)) * 8) + (l & 7)] = f2bf(Pv[nt][r]);
        }
      }
      for (int d = 0; d < 8; ++d)
        for (int r = 0; r < 4; ++r) Oacc[d][r] *= al[r];
      for (int ks = 0; ks < 2; ++ks) {
        int g = ks * 4 + quad;
        bf16x8 ap = *(const bf16x8*)&Ps[wave][l * 64 + (g ^ (l & 7)) * 8];
        for (int d = 0; d < 8; ++d) {
          bf16x8 bv = *(const bf16x8*)&Vsb[(d * 16 + l) * 64 + (g ^ (l & 7)) * 8];
          Oacc[d] = __builtin_amdgcn_mfma_f32_16x16x32_bf16(ap, bv, Oacc[d], 0, 0, 0);
        }
      }
    };

    // prologue: stage kt=0 into buf0 (prev half's end barrier guards WAR)
    fl_stage(Ks0, Vs0, K, Vt, kbase, vbase, 0, tid);
    __syncthreads();

    for (int kt = 0; kt <= qt; kt += 2) {
      if (kt + 1 <= qt) fl_stage(Ks1, Vs1, K, Vt, kbase, vbase, kt + 1, tid);
      fl_body(Ks0, Vs0, kt);
      __syncthreads();
      if (kt + 1 <= qt) {
        if (kt + 2 <= qt) fl_stage(Ks0, Vs0, K, Vt, kbase, vbase, kt + 2, tid);
        fl_body(Ks1, Vs1, kt + 1);
        __syncthreads();
      }
    }

    float inv[4];
    for (int r = 0; r < 4; ++r) inv[r] = 1.f / li[r];
    size_t obase = ((size_t)(b * 2048 + qt * 64 + wave * 16)) * 2048 + h * 128;
    for (int d = 0; d < 8; ++d)
      for (int r = 0; r < 4; ++r)
        O[obase + (size_t)(quad * 4 + r) * 2048 + d * 16 + l] = f2bf(Oacc[d][r] * inv[r]);
  }
}

// ---------------------------------------------------------------------------
extern "C" void kernel_launch(void* const* d_in, const int* in_sizes, int n_in,
                              void* d_out, int out_size, void* d_ws, size_t ws_size,
                              hipStream_t stream) {
  const void* X  = d_in[0];
  const void* Wq = d_in[3];
  const void* Wk = d_in[4];
  const void* Wv = d_in[5];
  const void* Wo = d_in[6];

  u16* base = (u16*)d_ws;
  int* flag = (int*)d_ws;
  const size_t TOK = 4096, DM = 2048;
  u16* Xbf = base + 128;               // 8M u16
  u16* Qw  = Xbf + TOK * DM;           // 8M
  u16* Kw  = Qw + TOK * DM;            // 8M
  u16* Vw  = Kw + TOK * DM;            // 8M (V, then attention output)
  u16* WT3 = Vw + TOK * DM;            // 12M u16: WqT ++ WkT ++ WvT (6144x2048)
  u16* Vtw = Xbf;                      // X dead after QKV gemm

  sniff_dtype<<<1, 256, 0, stream>>>((const unsigned*)X, flag);
  convert_x<<<4096, 256, 0, stream>>>(X, Xbf, flag);

  transpose_w<<<dim3(32, 32), 256, 0, stream>>>(Wq, WT3, flag);
  transpose_w<<<dim3(32, 32), 256, 0, stream>>>(Wk, WT3 + DM * DM, flag);
  transpose_w<<<dim3(32, 32), 256, 0, stream>>>(Wv, WT3 + 2 * DM * DM, flag);
  qkv_gemm<<<dim3(48, 32), 256, 0, stream>>>(Xbf, WT3, Qw, Kw, Vw);

  rope_k<<<dim3(512, 2), 256, 0, stream>>>(Qw, Kw);
  transpose_v<<<dim3(32, 2, 32), 256, 0, stream>>>(Vw, Vtw);
  flash_k<<<dim3(16, 16, 2), 256, 0, stream>>>(Qw, Kw, Vtw, Vw);

  transpose_w<<<dim3(32, 32), 256, 0, stream>>>(Wo, WT3, flag);
  gemm64_bt<<<dim3(32, 64), 256, 0, stream>>>(Vw, WT3, d_out, 4096, 2048, 2048, flag, 1);
}

// Round 10
// 466.250 us; speedup vs baseline: 1.5342x; 1.0233x over previous
//
#include <hip/hip_runtime.h>
#include <hip/hip_bf16.h>

typedef unsigned short u16;
typedef __bf16 bf16x8 __attribute__((ext_vector_type(8)));
typedef float f32x4 __attribute__((ext_vector_type(4)));
typedef unsigned short u16x8 __attribute__((ext_vector_type(8)));
typedef unsigned short u16x4 __attribute__((ext_vector_type(4)));

__device__ __forceinline__ u16 f2bf(float f) {
  union { float f; unsigned u; } v; v.f = f;
  unsigned r = (v.u + 0x7FFFu + ((v.u >> 16) & 1u)) >> 16;
  return (u16)r;
}
__device__ __forceinline__ float bf2f(u16 s) {
  union { unsigned u; float f; } v; v.u = ((unsigned)s) << 16;
  return v.f;
}
__device__ __forceinline__ f32x4 zero4() { f32x4 z = {0.f, 0.f, 0.f, 0.f}; return z; }

__device__ __forceinline__ void async16(void* lds, const void* g) {
  __builtin_amdgcn_global_load_lds(
      (__attribute__((address_space(1))) void*)(void*)g,
      (__attribute__((address_space(3))) void*)lds, 16, 0, 0);
}

// ---------------------------------------------------------------------------
// Dtype sniff: 1 = f32 inputs, 0 = bf16 inputs. Deterministic.
// ---------------------------------------------------------------------------
__global__ void sniff_dtype(const unsigned* __restrict__ X, int* __restrict__ flag) {
  __shared__ int cnt;
  if (threadIdx.x == 0) cnt = 0;
  __syncthreads();
  unsigned w = X[(size_t)threadIdx.x * 16384 + 1000];
  int e = (int)((w >> 7) & 0xFF);
  if (e >= 100 && e <= 150) atomicAdd(&cnt, 1);
  __syncthreads();
  if (threadIdx.x == 0) flag[0] = (cnt < 192) ? 1 : 0;
}

// ---------------------------------------------------------------------------
// X ingest -> bf16.
// ---------------------------------------------------------------------------
__global__ __launch_bounds__(256) void convert_x(
    const void* __restrict__ X, u16* __restrict__ dst, const int* __restrict__ flag) {
  const int mode = flag[0];
  size_t i8 = ((size_t)blockIdx.x * 256 + threadIdx.x) * 8;
  if (mode) {
    const float4* f = (const float4*)X;
    float4 a = f[i8 / 4], b = f[i8 / 4 + 1];
    u16x8 o;
    o[0] = f2bf(a.x); o[1] = f2bf(a.y); o[2] = f2bf(a.z); o[3] = f2bf(a.w);
    o[4] = f2bf(b.x); o[5] = f2bf(b.y); o[6] = f2bf(b.z); o[7] = f2bf(b.w);
    *(u16x8*)&dst[i8] = o;
  } else {
    *(u16x8*)&dst[i8] = *(const u16x8*)&((const u16*)X)[i8];
  }
}

// ---------------------------------------------------------------------------
// Output convert: Wf (f32, workspace) -> d_out (f32 if mode else bf16).
// ---------------------------------------------------------------------------
__global__ __launch_bounds__(256) void convert_out(
    const float* __restrict__ src, void* __restrict__ dst, const int* __restrict__ flag) {
  const int mode = flag[0];
  size_t i4 = ((size_t)blockIdx.x * 256 + threadIdx.x) * 4;
  float4 v = *(const float4*)&src[i4];
  if (mode) {
    *(float4*)&((float*)dst)[i4] = v;
  } else {
    u16x4 o;
    o[0] = f2bf(v.x); o[1] = f2bf(v.y); o[2] = f2bf(v.z); o[3] = f2bf(v.w);
    *(u16x4*)&((u16*)dst)[i4] = o;
  }
}

// ---------------------------------------------------------------------------
// Weight transpose + convert: Wt[n][k] = bf16(W[k][n]), 2048x2048.
// ---------------------------------------------------------------------------
__global__ __launch_bounds__(256) void transpose_w(
    const void* __restrict__ src, u16* __restrict__ d, const int* __restrict__ flag)
{
  __shared__ u16 t[64][65];
  const int mode = flag[0];
  int r0 = blockIdx.y * 64, c0 = blockIdx.x * 64;
  int tid = threadIdx.x;
  for (int j = 0; j < 2; ++j) {
    int idx = tid + j * 256;
    int r = idx >> 3, c = (idx & 7) * 8;
    size_t base = (size_t)(r0 + r) * 2048 + c0 + c;
    if (mode) {
      const float4* f = (const float4*)src;
      float4 a = f[base / 4], b = f[base / 4 + 1];
      t[r][c + 0] = f2bf(a.x); t[r][c + 1] = f2bf(a.y);
      t[r][c + 2] = f2bf(a.z); t[r][c + 3] = f2bf(a.w);
      t[r][c + 4] = f2bf(b.x); t[r][c + 5] = f2bf(b.y);
      t[r][c + 6] = f2bf(b.z); t[r][c + 7] = f2bf(b.w);
    } else {
      u16x8 v = *(const u16x8*)&((const u16*)src)[base];
      for (int q = 0; q < 8; ++q) t[r][c + q] = v[q];
    }
  }
  __syncthreads();
  for (int j = 0; j < 2; ++j) {
    int idx = tid + j * 256;
    int c = idx >> 3, r = (idx & 7) * 8;
    u16x8 v;
    for (int q = 0; q < 8; ++q) v[q] = t[r + q][c];
    *(u16x8*)&d[(size_t)(c0 + c) * 2048 + r0 + r] = v;
  }
}

// ---------------------------------------------------------------------------
// V transpose: Vt[(b*16+h)][d][kv] = V[b*2048+kv][h*128+d]
// ---------------------------------------------------------------------------
__global__ __launch_bounds__(256) void transpose_v(
    const u16* __restrict__ V, u16* __restrict__ Vt)
{
  __shared__ u16 t[64][65];
  int bh = blockIdx.z;
  int b = bh >> 4, h = bh & 15;
  int kv0 = blockIdx.x * 64, d0 = blockIdx.y * 64;
  int tid = threadIdx.x;
  for (int j = 0; j < 2; ++j) {
    int idx = tid + j * 256;
    int r = idx >> 3, c = (idx & 7) * 8;
    u16x8 v = *(const u16x8*)&V[(size_t)(b * 2048 + kv0 + r) * 2048 + h * 128 + d0 + c];
    for (int q = 0; q < 8; ++q) t[r][c + q] = v[q];
  }
  __syncthreads();
  for (int j = 0; j < 2; ++j) {
    int idx = tid + j * 256;
    int c = idx >> 3, r = (idx & 7) * 8;
    u16x8 v;
    for (int q = 0; q < 8; ++q) v[q] = t[r + q][c];
    *(u16x8*)&Vt[((size_t)bh * 128 + d0 + c) * 2048 + kv0 + r] = v;
  }
}

// ---------------------------------------------------------------------------
// RoPE in-place on Q and K (bf16) — trig reused across 4 heads (round-8 win).
// ---------------------------------------------------------------------------
__global__ __launch_bounds__(256) void rope_k(u16* __restrict__ Qp, u16* __restrict__ Kp)
{
  int idx = blockIdx.x * 256 + threadIdx.x;   // [0, 131072)
  u16* X = blockIdx.y ? Kp : Qp;
  int i8 = (idx & 7) * 8;                     // 8 slots of 8 within half-dh 64
  int hq = (idx >> 3) & 3;                    // head quad 0..3
  int tok = idx >> 5;                         // 0..4095
  int pos = tok & 2047;

  float c8[8], s8[8];
  for (int j = 0; j < 8; ++j) {
    float fi = (float)(i8 + j);
    float invf = __expf(fi * -0.14391156831212787f);  // ln(10000)/64
    float th = (float)pos * invf;
    sincosf(th, &s8[j], &c8[j]);
  }

  for (int hh = 0; hh < 4; ++hh) {
    int h = hq * 4 + hh;
    size_t base = (size_t)tok * 2048 + h * 128 + i8;
    u16x8 a = *(const u16x8*)&X[base];
    u16x8 bv = *(const u16x8*)&X[base + 64];
    u16x8 ra, rb;
    for (int j = 0; j < 8; ++j) {
      float x1 = bf2f(a[j]), x2 = bf2f(bv[j]);
      ra[j] = f2bf(x1 * c8[j] - x2 * s8[j]);
      rb[j] = f2bf(x2 * c8[j] + x1 * s8[j]);
    }
    *(u16x8*)&X[base] = ra;
    *(u16x8*)&X[base + 64] = rb;
  }
}

// ---------------------------------------------------------------------------
// Shared 128x128 GEMM machinery (m97-structure + depth-1 compile-time dbuf).
// ---------------------------------------------------------------------------
__device__ __forceinline__ void qkv_stage(
    u16* As, u16* Bs, const u16* A, const u16* Bt,
    int m0, int n0full, int kt, int tid, const int* rowA, const int* gA)
{
  for (int j = 0; j < 2; ++j) {
    int tf = tid + j * 256;
    async16(&As[tf * 8], &A[(size_t)(m0 + rowA[j]) * 2048 + kt + gA[j] * 8]);
    async16(&Bs[tf * 8], &Bt[(size_t)(n0full + rowA[j]) * 2048 + kt + gA[j] * 8]);
  }
}

__device__ __forceinline__ void qkv_compute(
    const u16* As, const u16* Bs, f32x4 (&acc)[4][4],
    int wr, int wc, int quad, int l)
{
  bf16x8 af[4], bfr[4];
  for (int mt = 0; mt < 4; ++mt) {
    int row = wr * 64 + mt * 16 + l;
    int g = quad ^ ((row >> 1) & 3);
    af[mt] = *(const bf16x8*)&As[row * 32 + g * 8];
  }
  for (int nt = 0; nt < 4; ++nt) {
    int row = wc * 64 + nt * 16 + l;
    int g = quad ^ ((row >> 1) & 3);
    bfr[nt] = *(const bf16x8*)&Bs[row * 32 + g * 8];
  }
  for (int mt = 0; mt < 4; ++mt)
    for (int nt = 0; nt < 4; ++nt)
      acc[mt][nt] = __builtin_amdgcn_mfma_f32_16x16x32_bf16(af[mt], bfr[nt], acc[mt][nt], 0, 0, 0);
}

// ---------------------------------------------------------------------------
// Fused QKV GEMM — unchanged (known-passing, ~135 µs / 764 TF).
// ---------------------------------------------------------------------------
__global__ __launch_bounds__(256) void qkv_gemm(
    const u16* __restrict__ A, const u16* __restrict__ Bt,
    u16* __restrict__ Qw, u16* __restrict__ Kw, u16* __restrict__ Vw)
{
  __shared__ __align__(16) u16 As0[128 * 32];
  __shared__ __align__(16) u16 Bs0[128 * 32];
  __shared__ __align__(16) u16 As1[128 * 32];
  __shared__ __align__(16) u16 Bs1[128 * 32];
  const int K = 2048, N = 2048;
  const int tid = threadIdx.x;
  const int wave = tid >> 6, lane = tid & 63;
  const int quad = lane >> 4, l = lane & 15;
  const int wr = wave >> 1, wc = wave & 1;
  const int m0 = blockIdx.y * 128, n0full = blockIdx.x * 128;
  const int mat = n0full >> 11;
  const int n0 = n0full & 2047;
  u16* C = (mat == 0) ? Qw : ((mat == 1) ? Kw : Vw);

  f32x4 acc[4][4];
  for (int i = 0; i < 4; ++i)
    for (int j = 0; j < 4; ++j) acc[i][j] = zero4();

  int rowA[2], gA[2];
  for (int j = 0; j < 2; ++j) {
    int tf = tid + j * 256;
    rowA[j] = tf >> 2;
    gA[j] = (tf & 3) ^ ((rowA[j] >> 1) & 3);
  }

  qkv_stage(As0, Bs0, A, Bt, m0, n0full, 0, tid, rowA, gA);
  __syncthreads();  // drain + visibility of buf0

  for (int kt = 0; kt < K; kt += 64) {
    qkv_stage(As1, Bs1, A, Bt, m0, n0full, kt + 32, tid, rowA, gA);
    qkv_compute(As0, Bs0, acc, wr, wc, quad, l);
    __syncthreads();  // drains buf1 loads (flew during compute) + WAR for buf0
    if (kt + 64 < K)
      qkv_stage(As0, Bs0, A, Bt, m0, n0full, kt + 64, tid, rowA, gA);
    qkv_compute(As1, Bs1, acc, wr, wc, quad, l);
    __syncthreads();
  }

  for (int mt = 0; mt < 4; ++mt)
    for (int nt = 0; nt < 4; ++nt)
      for (int r = 0; r < 4; ++r) {
        int m = m0 + wr * 64 + mt * 16 + quad * 4 + r;
        int n = n0 + wc * 64 + nt * 16 + l;
        C[(size_t)m * N + n] = f2bf(acc[mt][nt][r]);
      }
}

// ---------------------------------------------------------------------------
// Wo GEMM — 128x128 m97-structure, f32 output to WORKSPACE (proven-clean
// write path; round-7's d_out-direct version amplified writes 55x).
// convert_out does the dtype dispatch to d_out.
// ---------------------------------------------------------------------------
__global__ __launch_bounds__(256) void gemm128_wo(
    const u16* __restrict__ A, const u16* __restrict__ Bt, float* __restrict__ Wf)
{
  __shared__ __align__(16) u16 As0[128 * 32];
  __shared__ __align__(16) u16 Bs0[128 * 32];
  __shared__ __align__(16) u16 As1[128 * 32];
  __shared__ __align__(16) u16 Bs1[128 * 32];
  const int K = 2048, N = 2048;
  const int tid = threadIdx.x;
  const int wave = tid >> 6, lane = tid & 63;
  const int quad = lane >> 4, l = lane & 15;
  const int wr = wave >> 1, wc = wave & 1;
  const int m0 = blockIdx.y * 128, n0 = blockIdx.x * 128;

  f32x4 acc[4][4];
  for (int i = 0; i < 4; ++i)
    for (int j = 0; j < 4; ++j) acc[i][j] = zero4();

  int rowA[2], gA[2];
  for (int j = 0; j < 2; ++j) {
    int tf = tid + j * 256;
    rowA[j] = tf >> 2;
    gA[j] = (tf & 3) ^ ((rowA[j] >> 1) & 3);
  }

  qkv_stage(As0, Bs0, A, Bt, m0, n0, 0, tid, rowA, gA);
  __syncthreads();

  for (int kt = 0; kt < K; kt += 64) {
    qkv_stage(As1, Bs1, A, Bt, m0, n0, kt + 32, tid, rowA, gA);
    qkv_compute(As0, Bs0, acc, wr, wc, quad, l);
    __syncthreads();
    if (kt + 64 < K)
      qkv_stage(As0, Bs0, A, Bt, m0, n0, kt + 64, tid, rowA, gA);
    qkv_compute(As1, Bs1, acc, wr, wc, quad, l);
    __syncthreads();
  }

  for (int mt = 0; mt < 4; ++mt)
    for (int nt = 0; nt < 4; ++nt)
      for (int r = 0; r < 4; ++r) {
        int m = m0 + wr * 64 + mt * 16 + quad * 4 + r;
        int n = n0 + wc * 64 + nt * 16 + l;
        Wf[(size_t)m * N + n] = acc[mt][nt][r];
      }
}

// ---------------------------------------------------------------------------
// Flash attention, causal — unchanged (causal-paired balanced grid +
// depth-1 compile-time dbuf pipeline).
// ---------------------------------------------------------------------------
__device__ __forceinline__ void fl_stage(
    u16* Ks, u16* Vs, const u16* K, const u16* Vt,
    size_t kbase, size_t vbase, int kt, int tid)
{
  for (int j = 0; j < 4; ++j) {
    int tf = tid + j * 256;
    int row = tf >> 4, p = tf & 15;
    int g = p ^ (row & 7);
    async16(&Ks[tf * 8], &K[kbase + (size_t)(kt * 64 + row) * 2048 + g * 8]);
  }
  for (int j = 0; j < 4; ++j) {
    int tf = tid + j * 256;
    int row = tf >> 3, p = tf & 7;
    int g = p ^ (row & 7);
    async16(&Vs[tf * 8], &Vt[vbase + (size_t)row * 2048 + kt * 64 + g * 8]);
  }
}

__global__ __launch_bounds__(256) void flash_k(
    const u16* __restrict__ Q, const u16* __restrict__ K,
    const u16* __restrict__ Vt, u16* __restrict__ O)
{
  __shared__ __align__(16) u16 Ks0[64 * 128];
  __shared__ __align__(16) u16 Vs0[128 * 64];
  __shared__ __align__(16) u16 Ks1[64 * 128];
  __shared__ __align__(16) u16 Vs1[128 * 64];
  __shared__ __align__(16) u16 Ps[4][16 * 64];

  const int tid = threadIdx.x;
  const int wave = tid >> 6, lane = tid & 63;
  const int quad = lane >> 4, l = lane & 15;
  const int pair = blockIdx.x;            // 0..15
  const int h = blockIdx.y, b = blockIdx.z;

  const size_t kbase = ((size_t)b * 2048) * 2048 + h * 128;
  const size_t vbase = ((size_t)(b * 16 + h)) * 128 * 2048;

  for (int half = 0; half < 2; ++half) {
    const int qt = half ? pair : (31 - pair);  // big tile first

    const size_t qoff = ((size_t)(b * 2048 + qt * 64)) * 2048 + h * 128;
    bf16x8 qf[4];
    for (int ks = 0; ks < 4; ++ks)
      qf[ks] = *(const bf16x8*)&Q[qoff + (size_t)(wave * 16 + l) * 2048 + (ks * 4 + quad) * 8];

    f32x4 Oacc[8];
    for (int i = 0; i < 8; ++i) Oacc[i] = zero4();
    float mi[4] = {-3e38f, -3e38f, -3e38f, -3e38f};
    float li[4] = {0.f, 0.f, 0.f, 0.f};

    auto fl_body = [&](const u16* Ksb, const u16* Vsb, int kt) {
      f32x4 S[4];
      for (int nt = 0; nt < 4; ++nt) S[nt] = zero4();
      for (int ks = 0; ks < 4; ++ks) {
        int g = ks * 4 + quad;
        for (int nt = 0; nt < 4; ++nt) {
          bf16x8 bk = *(const bf16x8*)&Ksb[(nt * 16 + l) * 128 + (g ^ (l & 7)) * 8];
          S[nt] = __builtin_amdgcn_mfma_f32_16x16x32_bf16(qf[ks], bk, S[nt], 0, 0, 0);
        }
      }

      const bool dg = (kt == qt);
      float Pv[4][4];
      float rm[4] = {-3e38f, -3e38f, -3e38f, -3e38f};
      for (int nt = 0; nt < 4; ++nt)
        for (int r = 0; r < 4; ++r) {
          float s = S[nt][r] * 0.08838834764831845f;  // 1/sqrt(128)
          if (dg && (nt * 16 + l > wave * 16 + quad * 4 + r)) s = -3e38f;
          Pv[nt][r] = s;
          rm[r] = fmaxf(rm[r], s);
        }
      for (int r = 0; r < 4; ++r)
        for (int off = 1; off < 16; off <<= 1)
          rm[r] = fmaxf(rm[r], __shfl_xor(rm[r], off));
      float al[4], rs[4];
      for (int r = 0; r < 4; ++r) {
        float mn = fmaxf(mi[r], rm[r]);
        al[r] = __expf(mi[r] - mn);
        mi[r] = mn;
        rs[r] = 0.f;
      }
      for (int nt = 0; nt < 4; ++nt)
        for (int r = 0; r < 4; ++r) {
          float p = __expf(Pv[nt][r] - mi[r]);
          Pv[nt][r] = p;
          rs[r] += p;
        }
      for (int r = 0; r < 4; ++r) {
        for (int off = 1; off < 16; off <<= 1)
          rs[r] += __shfl_xor(rs[r], off);
        li[r] = li[r] * al[r] + rs[r];
      }
      for (int nt = 0; nt < 4; ++nt) {
        int gc = nt * 2 + (l >> 3);
        for (int r = 0; r < 4; ++r) {
          int row = quad * 4 + r;
          Ps[wave][row * 64 + ((gc ^ (row & 7)) * 8) + (l & 7)] = f2bf(Pv[nt][r]);
        }
      }
      for (int d = 0; d < 8; ++d)
        for (int r = 0; r < 4; ++r) Oacc[d][r] *= al[r];
      for (int ks = 0; ks < 2; ++ks) {
        int g = ks * 4 + quad;
        bf16x8 ap = *(const bf16x8*)&Ps[wave][l * 64 + (g ^ (l & 7)) * 8];
        for (int d = 0; d < 8; ++d) {
          bf16x8 bv = *(const bf16x8*)&Vsb[(d * 16 + l) * 64 + (g ^ (l & 7)) * 8];
          Oacc[d] = __builtin_amdgcn_mfma_f32_16x16x32_bf16(ap, bv, Oacc[d], 0, 0, 0);
        }
      }
    };

    // prologue: stage kt=0 into buf0 (prev half's end barrier guards WAR)
    fl_stage(Ks0, Vs0, K, Vt, kbase, vbase, 0, tid);
    __syncthreads();

    for (int kt = 0; kt <= qt; kt += 2) {
      if (kt + 1 <= qt) fl_stage(Ks1, Vs1, K, Vt, kbase, vbase, kt + 1, tid);
      fl_body(Ks0, Vs0, kt);
      __syncthreads();
      if (kt + 1 <= qt) {
        if (kt + 2 <= qt) fl_stage(Ks0, Vs0, K, Vt, kbase, vbase, kt + 2, tid);
        fl_body(Ks1, Vs1, kt + 1);
        __syncthreads();
      }
    }

    float inv[4];
    for (int r = 0; r < 4; ++r) inv[r] = 1.f / li[r];
    size_t obase = ((size_t)(b * 2048 + qt * 64 + wave * 16)) * 2048 + h * 128;
    for (int d = 0; d < 8; ++d)
      for (int r = 0; r < 4; ++r)
        O[obase + (size_t)(quad * 4 + r) * 2048 + d * 16 + l] = f2bf(Oacc[d][r] * inv[r]);
  }
}

// ---------------------------------------------------------------------------
extern "C" void kernel_launch(void* const* d_in, const int* in_sizes, int n_in,
                              void* d_out, int out_size, void* d_ws, size_t ws_size,
                              hipStream_t stream) {
  const void* X  = d_in[0];
  const void* Wq = d_in[3];
  const void* Wk = d_in[4];
  const void* Wv = d_in[5];
  const void* Wo = d_in[6];

  u16* base = (u16*)d_ws;
  int* flag = (int*)d_ws;
  const size_t TOK = 4096, DM = 2048;
  u16* Xbf = base + 128;               // 8M u16
  u16* Qw  = Xbf + TOK * DM;           // 8M
  u16* Kw  = Qw + TOK * DM;            // 8M
  u16* Vw  = Kw + TOK * DM;            // 8M (V, then attention output)
  u16* WT3 = Vw + TOK * DM;            // 12M u16: WqT ++ WkT ++ WvT (6144x2048)
  u16* Vtw = Xbf;                      // X dead after QKV gemm
  float* Wf = (float*)Xbf;             // f32 Wo-GEMM out: 33.5MB over Xbf+Qw+
                                       // head of Kw (all dead at Wo time)

  sniff_dtype<<<1, 256, 0, stream>>>((const unsigned*)X, flag);
  convert_x<<<4096, 256, 0, stream>>>(X, Xbf, flag);

  transpose_w<<<dim3(32, 32), 256, 0, stream>>>(Wq, WT3, flag);
  transpose_w<<<dim3(32, 32), 256, 0, stream>>>(Wk, WT3 + DM * DM, flag);
  transpose_w<<<dim3(32, 32), 256, 0, stream>>>(Wv, WT3 + 2 * DM * DM, flag);
  qkv_gemm<<<dim3(48, 32), 256, 0, stream>>>(Xbf, WT3, Qw, Kw, Vw);

  rope_k<<<dim3(512, 2), 256, 0, stream>>>(Qw, Kw);
  transpose_v<<<dim3(32, 2, 32), 256, 0, stream>>>(Vw, Vtw);
  flash_k<<<dim3(16, 16, 2), 256, 0, stream>>>(Qw, Kw, Vtw, Vw);

  transpose_w<<<dim3(32, 32), 256, 0, stream>>>(Wo, WT3, flag);
  gemm128_wo<<<dim3(16, 32), 256, 0, stream>>>(Vw, WT3, Wf);
  convert_out<<<8192, 256, 0, stream>>>(Wf, d_out, flag);
}

// Round 12
// 460.406 us; speedup vs baseline: 1.5537x; 1.0127x over previous
//
#include <hip/hip_runtime.h>
#include <hip/hip_bf16.h>

typedef unsigned short u16;
typedef __bf16 bf16x8 __attribute__((ext_vector_type(8)));
typedef float f32x4 __attribute__((ext_vector_type(4)));
typedef unsigned short u16x8 __attribute__((ext_vector_type(8)));
typedef unsigned short u16x4 __attribute__((ext_vector_type(4)));

__device__ __forceinline__ u16 f2bf(float f) {
  union { float f; unsigned u; } v; v.f = f;
  unsigned r = (v.u + 0x7FFFu + ((v.u >> 16) & 1u)) >> 16;
  return (u16)r;
}
__device__ __forceinline__ float bf2f(u16 s) {
  union { unsigned u; float f; } v; v.u = ((unsigned)s) << 16;
  return v.f;
}
__device__ __forceinline__ f32x4 zero4() { f32x4 z = {0.f, 0.f, 0.f, 0.f}; return z; }

__device__ __forceinline__ void async16(void* lds, const void* g) {
  __builtin_amdgcn_global_load_lds(
      (__attribute__((address_space(1))) void*)(void*)g,
      (__attribute__((address_space(3))) void*)lds, 16, 0, 0);
}
// NOTE (round-11 post-mortem): passing a nonzero IMMEDIATE in the builtin's
// offset argument produced NaN output — the imm field's semantics for the
// LDS-DMA instruction are not "+N on the global address". Express offsets as
// pointer arithmetic instead; the compiler folds them only where legal.

// ---------------------------------------------------------------------------
// Dtype sniff: 1 = f32 inputs, 0 = bf16 inputs. Deterministic.
// ---------------------------------------------------------------------------
__global__ void sniff_dtype(const unsigned* __restrict__ X, int* __restrict__ flag) {
  __shared__ int cnt;
  if (threadIdx.x == 0) cnt = 0;
  __syncthreads();
  unsigned w = X[(size_t)threadIdx.x * 16384 + 1000];
  int e = (int)((w >> 7) & 0xFF);
  if (e >= 100 && e <= 150) atomicAdd(&cnt, 1);
  __syncthreads();
  if (threadIdx.x == 0) flag[0] = (cnt < 192) ? 1 : 0;
}

// ---------------------------------------------------------------------------
// X ingest -> bf16.
// ---------------------------------------------------------------------------
__global__ __launch_bounds__(256) void convert_x(
    const void* __restrict__ X, u16* __restrict__ dst, const int* __restrict__ flag) {
  const int mode = flag[0];
  size_t i8 = ((size_t)blockIdx.x * 256 + threadIdx.x) * 8;
  if (mode) {
    const float4* f = (const float4*)X;
    float4 a = f[i8 / 4], b = f[i8 / 4 + 1];
    u16x8 o;
    o[0] = f2bf(a.x); o[1] = f2bf(a.y); o[2] = f2bf(a.z); o[3] = f2bf(a.w);
    o[4] = f2bf(b.x); o[5] = f2bf(b.y); o[6] = f2bf(b.z); o[7] = f2bf(b.w);
    *(u16x8*)&dst[i8] = o;
  } else {
    *(u16x8*)&dst[i8] = *(const u16x8*)&((const u16*)X)[i8];
  }
}

// ---------------------------------------------------------------------------
// Output convert: Wf (f32, workspace) -> d_out (f32 if mode else bf16).
// ---------------------------------------------------------------------------
__global__ __launch_bounds__(256) void convert_out(
    const float* __restrict__ src, void* __restrict__ dst, const int* __restrict__ flag) {
  const int mode = flag[0];
  size_t i4 = ((size_t)blockIdx.x * 256 + threadIdx.x) * 4;
  float4 v = *(const float4*)&src[i4];
  if (mode) {
    *(float4*)&((float*)dst)[i4] = v;
  } else {
    u16x4 o;
    o[0] = f2bf(v.x); o[1] = f2bf(v.y); o[2] = f2bf(v.z); o[3] = f2bf(v.w);
    *(u16x4*)&((u16*)dst)[i4] = o;
  }
}

// ---------------------------------------------------------------------------
// Weight transpose + convert: Wt[n][k] = bf16(W[k][n]), 2048x2048.
// ---------------------------------------------------------------------------
__global__ __launch_bounds__(256) void transpose_w(
    const void* __restrict__ src, u16* __restrict__ d, const int* __restrict__ flag)
{
  __shared__ u16 t[64][65];
  const int mode = flag[0];
  int r0 = blockIdx.y * 64, c0 = blockIdx.x * 64;
  int tid = threadIdx.x;
  for (int j = 0; j < 2; ++j) {
    int idx = tid + j * 256;
    int r = idx >> 3, c = (idx & 7) * 8;
    size_t base = (size_t)(r0 + r) * 2048 + c0 + c;
    if (mode) {
      const float4* f = (const float4*)src;
      float4 a = f[base / 4], b = f[base / 4 + 1];
      t[r][c + 0] = f2bf(a.x); t[r][c + 1] = f2bf(a.y);
      t[r][c + 2] = f2bf(a.z); t[r][c + 3] = f2bf(a.w);
      t[r][c + 4] = f2bf(b.x); t[r][c + 5] = f2bf(b.y);
      t[r][c + 6] = f2bf(b.z); t[r][c + 7] = f2bf(b.w);
    } else {
      u16x8 v = *(const u16x8*)&((const u16*)src)[base];
      for (int q = 0; q < 8; ++q) t[r][c + q] = v[q];
    }
  }
  __syncthreads();
  for (int j = 0; j < 2; ++j) {
    int idx = tid + j * 256;
    int c = idx >> 3, r = (idx & 7) * 8;
    u16x8 v;
    for (int q = 0; q < 8; ++q) v[q] = t[r + q][c];
    *(u16x8*)&d[(size_t)(c0 + c) * 2048 + r0 + r] = v;
  }
}

// ---------------------------------------------------------------------------
// V transpose: Vt[(b*16+h)][d][kv] = V[b*2048+kv][h*128+d]
// ---------------------------------------------------------------------------
__global__ __launch_bounds__(256) void transpose_v(
    const u16* __restrict__ V, u16* __restrict__ Vt)
{
  __shared__ u16 t[64][65];
  int bh = blockIdx.z;
  int b = bh >> 4, h = bh & 15;
  int kv0 = blockIdx.x * 64, d0 = blockIdx.y * 64;
  int tid = threadIdx.x;
  for (int j = 0; j < 2; ++j) {
    int idx = tid + j * 256;
    int r = idx >> 3, c = (idx & 7) * 8;
    u16x8 v = *(const u16x8*)&V[(size_t)(b * 2048 + kv0 + r) * 2048 + h * 128 + d0 + c];
    for (int q = 0; q < 8; ++q) t[r][c + q] = v[q];
  }
  __syncthreads();
  for (int j = 0; j < 2; ++j) {
    int idx = tid + j * 256;
    int c = idx >> 3, r = (idx & 7) * 8;
    u16x8 v;
    for (int q = 0; q < 8; ++q) v[q] = t[r + q][c];
    *(u16x8*)&Vt[((size_t)bh * 128 + d0 + c) * 2048 + kv0 + r] = v;
  }
}

// ---------------------------------------------------------------------------
// RoPE in-place on Q and K (bf16) — trig reused across 4 heads (round-8 win).
// ---------------------------------------------------------------------------
__global__ __launch_bounds__(256) void rope_k(u16* __restrict__ Qp, u16* __restrict__ Kp)
{
  int idx = blockIdx.x * 256 + threadIdx.x;   // [0, 131072)
  u16* X = blockIdx.y ? Kp : Qp;
  int i8 = (idx & 7) * 8;                     // 8 slots of 8 within half-dh 64
  int hq = (idx >> 3) & 3;                    // head quad 0..3
  int tok = idx >> 5;                         // 0..4095
  int pos = tok & 2047;

  float c8[8], s8[8];
  for (int j = 0; j < 8; ++j) {
    float fi = (float)(i8 + j);
    float invf = __expf(fi * -0.14391156831212787f);  // ln(10000)/64
    float th = (float)pos * invf;
    sincosf(th, &s8[j], &c8[j]);
  }

  for (int hh = 0; hh < 4; ++hh) {
    int h = hq * 4 + hh;
    size_t base = (size_t)tok * 2048 + h * 128 + i8;
    u16x8 a = *(const u16x8*)&X[base];
    u16x8 bv = *(const u16x8*)&X[base + 64];
    u16x8 ra, rb;
    for (int j = 0; j < 8; ++j) {
      float x1 = bf2f(a[j]), x2 = bf2f(bv[j]);
      ra[j] = f2bf(x1 * c8[j] - x2 * s8[j]);
      rb[j] = f2bf(x2 * c8[j] + x1 * s8[j]);
    }
    *(u16x8*)&X[base] = ra;
    *(u16x8*)&X[base + 64] = rb;
  }
}

// ---------------------------------------------------------------------------
// Shared 128x128 GEMM compute (m97-structure). ROUND-18 DELTA: staging uses
// precomputed per-thread global pointers advanced by += 64/iter; the +32/+64
// element offsets are POINTER ARITHMETIC (compiler folds to imm only where
// legal) — NOT the builtin's imm-offset arg (round-11 NaN).
// ---------------------------------------------------------------------------
__device__ __forceinline__ void qkv_compute(
    const u16* As, const u16* Bs, f32x4 (&acc)[4][4],
    int wr, int wc, int quad, int l)
{
  bf16x8 af[4], bfr[4];
  for (int mt = 0; mt < 4; ++mt) {
    int row = wr * 64 + mt * 16 + l;
    int g = quad ^ ((row >> 1) & 3);
    af[mt] = *(const bf16x8*)&As[row * 32 + g * 8];
  }
  for (int nt = 0; nt < 4; ++nt) {
    int row = wc * 64 + nt * 16 + l;
    int g = quad ^ ((row >> 1) & 3);
    bfr[nt] = *(const bf16x8*)&Bs[row * 32 + g * 8];
  }
  for (int mt = 0; mt < 4; ++mt)
    for (int nt = 0; nt < 4; ++nt)
      acc[mt][nt] = __builtin_amdgcn_mfma_f32_16x16x32_bf16(af[mt], bfr[nt], acc[mt][nt], 0, 0, 0);
}

// ---------------------------------------------------------------------------
// Fused QKV GEMM — pointer-increment staging (round-18, safe form).
// ---------------------------------------------------------------------------
__global__ __launch_bounds__(256) void qkv_gemm(
    const u16* __restrict__ A, const u16* __restrict__ Bt,
    u16* __restrict__ Qw, u16* __restrict__ Kw, u16* __restrict__ Vw)
{
  __shared__ __align__(16) u16 As0[128 * 32];
  __shared__ __align__(16) u16 Bs0[128 * 32];
  __shared__ __align__(16) u16 As1[128 * 32];
  __shared__ __align__(16) u16 Bs1[128 * 32];
  const int K = 2048, N = 2048;
  const int tid = threadIdx.x;
  const int wave = tid >> 6, lane = tid & 63;
  const int quad = lane >> 4, l = lane & 15;
  const int wr = wave >> 1, wc = wave & 1;
  const int m0 = blockIdx.y * 128, n0full = blockIdx.x * 128;
  const int mat = n0full >> 11;
  const int n0 = n0full & 2047;
  u16* C = (mat == 0) ? Qw : ((mat == 1) ? Kw : Vw);

  f32x4 acc[4][4];
  for (int i = 0; i < 4; ++i)
    for (int j = 0; j < 4; ++j) acc[i][j] = zero4();

  const int rowA0 = tid >> 2;
  const int gA0 = (tid & 3) ^ ((rowA0 >> 1) & 3);
  const int rowA1 = (tid + 256) >> 2;
  const int gA1 = ((tid + 256) & 3) ^ ((rowA1 >> 1) & 3);

  const u16* pA0 = &A[(size_t)(m0 + rowA0) * 2048 + gA0 * 8];
  const u16* pA1 = &A[(size_t)(m0 + rowA1) * 2048 + gA1 * 8];
  const u16* pB0 = &Bt[(size_t)(n0full + rowA0) * 2048 + gA0 * 8];
  const u16* pB1 = &Bt[(size_t)(n0full + rowA1) * 2048 + gA1 * 8];

  u16* dA0s0 = &As0[tid * 8];        u16* dA1s0 = &As0[(tid + 256) * 8];
  u16* dB0s0 = &Bs0[tid * 8];        u16* dB1s0 = &Bs0[(tid + 256) * 8];
  u16* dA0s1 = &As1[tid * 8];        u16* dA1s1 = &As1[(tid + 256) * 8];
  u16* dB0s1 = &Bs1[tid * 8];        u16* dB1s1 = &Bs1[(tid + 256) * 8];

  // prologue: kt=0 into buf0
  async16(dA0s0, pA0); async16(dA1s0, pA1);
  async16(dB0s0, pB0); async16(dB1s0, pB1);
  __syncthreads();

  for (int kt = 0; kt < K; kt += 64) {
    // stage buf1 = kt+32 (pointer + 32 elems), flies under compute of buf0
    async16(dA0s1, pA0 + 32); async16(dA1s1, pA1 + 32);
    async16(dB0s1, pB0 + 32); async16(dB1s1, pB1 + 32);
    qkv_compute(As0, Bs0, acc, wr, wc, quad, l);
    __syncthreads();
    if (kt + 64 < K) {
      // stage buf0 = kt+64 (pointer + 64 elems), flies under compute of buf1
      async16(dA0s0, pA0 + 64); async16(dA1s0, pA1 + 64);
      async16(dB0s0, pB0 + 64); async16(dB1s0, pB1 + 64);
    }
    qkv_compute(As1, Bs1, acc, wr, wc, quad, l);
    __syncthreads();
    pA0 += 64; pA1 += 64; pB0 += 64; pB1 += 64;
  }

  for (int mt = 0; mt < 4; ++mt)
    for (int nt = 0; nt < 4; ++nt)
      for (int r = 0; r < 4; ++r) {
        int m = m0 + wr * 64 + mt * 16 + quad * 4 + r;
        int n = n0 + wc * 64 + nt * 16 + l;
        C[(size_t)m * N + n] = f2bf(acc[mt][nt][r]);
      }
}

// ---------------------------------------------------------------------------
// Wo GEMM — 128x128, f32 to WORKSPACE (clean write path), pointer-increment
// staging (round-18, safe form). convert_out does the d_out dtype dispatch.
// ---------------------------------------------------------------------------
__global__ __launch_bounds__(256) void gemm128_wo(
    const u16* __restrict__ A, const u16* __restrict__ Bt, float* __restrict__ Wf)
{
  __shared__ __align__(16) u16 As0[128 * 32];
  __shared__ __align__(16) u16 Bs0[128 * 32];
  __shared__ __align__(16) u16 As1[128 * 32];
  __shared__ __align__(16) u16 Bs1[128 * 32];
  const int K = 2048, N = 2048;
  const int tid = threadIdx.x;
  const int wave = tid >> 6, lane = tid & 63;
  const int quad = lane >> 4, l = lane & 15;
  const int wr = wave >> 1, wc = wave & 1;
  const int m0 = blockIdx.y * 128, n0 = blockIdx.x * 128;

  f32x4 acc[4][4];
  for (int i = 0; i < 4; ++i)
    for (int j = 0; j < 4; ++j) acc[i][j] = zero4();

  const int rowA0 = tid >> 2;
  const int gA0 = (tid & 3) ^ ((rowA0 >> 1) & 3);
  const int rowA1 = (tid + 256) >> 2;
  const int gA1 = ((tid + 256) & 3) ^ ((rowA1 >> 1) & 3);

  const u16* pA0 = &A[(size_t)(m0 + rowA0) * 2048 + gA0 * 8];
  const u16* pA1 = &A[(size_t)(m0 + rowA1) * 2048 + gA1 * 8];
  const u16* pB0 = &Bt[(size_t)(n0 + rowA0) * 2048 + gA0 * 8];
  const u16* pB1 = &Bt[(size_t)(n0 + rowA1) * 2048 + gA1 * 8];

  u16* dA0s0 = &As0[tid * 8];        u16* dA1s0 = &As0[(tid + 256) * 8];
  u16* dB0s0 = &Bs0[tid * 8];        u16* dB1s0 = &Bs0[(tid + 256) * 8];
  u16* dA0s1 = &As1[tid * 8];        u16* dA1s1 = &As1[(tid + 256) * 8];
  u16* dB0s1 = &Bs1[tid * 8];        u16* dB1s1 = &Bs1[(tid + 256) * 8];

  async16(dA0s0, pA0); async16(dA1s0, pA1);
  async16(dB0s0, pB0); async16(dB1s0, pB1);
  __syncthreads();

  for (int kt = 0; kt < K; kt += 64) {
    async16(dA0s1, pA0 + 32); async16(dA1s1, pA1 + 32);
    async16(dB0s1, pB0 + 32); async16(dB1s1, pB1 + 32);
    qkv_compute(As0, Bs0, acc, wr, wc, quad, l);
    __syncthreads();
    if (kt + 64 < K) {
      async16(dA0s0, pA0 + 64); async16(dA1s0, pA1 + 64);
      async16(dB0s0, pB0 + 64); async16(dB1s0, pB1 + 64);
    }
    qkv_compute(As1, Bs1, acc, wr, wc, quad, l);
    __syncthreads();
    pA0 += 64; pA1 += 64; pB0 += 64; pB1 += 64;
  }

  for (int mt = 0; mt < 4; ++mt)
    for (int nt = 0; nt < 4; ++nt)
      for (int r = 0; r < 4; ++r) {
        int m = m0 + wr * 64 + mt * 16 + quad * 4 + r;
        int n = n0 + wc * 64 + nt * 16 + l;
        Wf[(size_t)m * N + n] = acc[mt][nt][r];
      }
}

// ---------------------------------------------------------------------------
// Flash attention, causal — unchanged (causal-paired balanced grid +
// depth-1 compile-time dbuf pipeline).
// ---------------------------------------------------------------------------
__device__ __forceinline__ void fl_stage(
    u16* Ks, u16* Vs, const u16* K, const u16* Vt,
    size_t kbase, size_t vbase, int kt, int tid)
{
  for (int j = 0; j < 4; ++j) {
    int tf = tid + j * 256;
    int row = tf >> 4, p = tf & 15;
    int g = p ^ (row & 7);
    async16(&Ks[tf * 8], &K[kbase + (size_t)(kt * 64 + row) * 2048 + g * 8]);
  }
  for (int j = 0; j < 4; ++j) {
    int tf = tid + j * 256;
    int row = tf >> 3, p = tf & 7;
    int g = p ^ (row & 7);
    async16(&Vs[tf * 8], &Vt[vbase + (size_t)row * 2048 + kt * 64 + g * 8]);
  }
}

__global__ __launch_bounds__(256) void flash_k(
    const u16* __restrict__ Q, const u16* __restrict__ K,
    const u16* __restrict__ Vt, u16* __restrict__ O)
{
  __shared__ __align__(16) u16 Ks0[64 * 128];
  __shared__ __align__(16) u16 Vs0[128 * 64];
  __shared__ __align__(16) u16 Ks1[64 * 128];
  __shared__ __align__(16) u16 Vs1[128 * 64];
  __shared__ __align__(16) u16 Ps[4][16 * 64];

  const int tid = threadIdx.x;
  const int wave = tid >> 6, lane = tid & 63;
  const int quad = lane >> 4, l = lane & 15;
  const int pair = blockIdx.x;            // 0..15
  const int h = blockIdx.y, b = blockIdx.z;

  const size_t kbase = ((size_t)b * 2048) * 2048 + h * 128;
  const size_t vbase = ((size_t)(b * 16 + h)) * 128 * 2048;

  for (int half = 0; half < 2; ++half) {
    const int qt = half ? pair : (31 - pair);  // big tile first

    const size_t qoff = ((size_t)(b * 2048 + qt * 64)) * 2048 + h * 128;
    bf16x8 qf[4];
    for (int ks = 0; ks < 4; ++ks)
      qf[ks] = *(const bf16x8*)&Q[qoff + (size_t)(wave * 16 + l) * 2048 + (ks * 4 + quad) * 8];

    f32x4 Oacc[8];
    for (int i = 0; i < 8; ++i) Oacc[i] = zero4();
    float mi[4] = {-3e38f, -3e38f, -3e38f, -3e38f};
    float li[4] = {0.f, 0.f, 0.f, 0.f};

    auto fl_body = [&](const u16* Ksb, const u16* Vsb, int kt) {
      f32x4 S[4];
      for (int nt = 0; nt < 4; ++nt) S[nt] = zero4();
      for (int ks = 0; ks < 4; ++ks) {
        int g = ks * 4 + quad;
        for (int nt = 0; nt < 4; ++nt) {
          bf16x8 bk = *(const bf16x8*)&Ksb[(nt * 16 + l) * 128 + (g ^ (l & 7)) * 8];
          S[nt] = __builtin_amdgcn_mfma_f32_16x16x32_bf16(qf[ks], bk, S[nt], 0, 0, 0);
        }
      }

      const bool dg = (kt == qt);
      float Pv[4][4];
      float rm[4] = {-3e38f, -3e38f, -3e38f, -3e38f};
      for (int nt = 0; nt < 4; ++nt)
        for (int r = 0; r < 4; ++r) {
          float s = S[nt][r] * 0.08838834764831845f;  // 1/sqrt(128)
          if (dg && (nt * 16 + l > wave * 16 + quad * 4 + r)) s = -3e38f;
          Pv[nt][r] = s;
          rm[r] = fmaxf(rm[r], s);
        }
      for (int r = 0; r < 4; ++r)
        for (int off = 1; off < 16; off <<= 1)
          rm[r] = fmaxf(rm[r], __shfl_xor(rm[r], off));
      float al[4], rs[4];
      for (int r = 0; r < 4; ++r) {
        float mn = fmaxf(mi[r], rm[r]);
        al[r] = __expf(mi[r] - mn);
        mi[r] = mn;
        rs[r] = 0.f;
      }
      for (int nt = 0; nt < 4; ++nt)
        for (int r = 0; r < 4; ++r) {
          float p = __expf(Pv[nt][r] - mi[r]);
          Pv[nt][r] = p;
          rs[r] += p;
        }
      for (int r = 0; r < 4; ++r) {
        for (int off = 1; off < 16; off <<= 1)
          rs[r] += __shfl_xor(rs[r], off);
        li[r] = li[r] * al[r] + rs[r];
      }
      for (int nt = 0; nt < 4; ++nt) {
        int gc = nt * 2 + (l >> 3);
        for (int r = 0; r < 4; ++r) {
          int row = quad * 4 + r;
          Ps[wave][row * 64 + ((gc ^ (row & 7)) * 8) + (l & 7)] = f2bf(Pv[nt][r]);
        }
      }
      for (int d = 0; d < 8; ++d)
        for (int r = 0; r < 4; ++r) Oacc[d][r] *= al[r];
      for (int ks = 0; ks < 2; ++ks) {
        int g = ks * 4 + quad;
        bf16x8 ap = *(const bf16x8*)&Ps[wave][l * 64 + (g ^ (l & 7)) * 8];
        for (int d = 0; d < 8; ++d) {
          bf16x8 bv = *(const bf16x8*)&Vsb[(d * 16 + l) * 64 + (g ^ (l & 7)) * 8];
          Oacc[d] = __builtin_amdgcn_mfma_f32_16x16x32_bf16(ap, bv, Oacc[d], 0, 0, 0);
        }
      }
    };

    // prologue: stage kt=0 into buf0 (prev half's end barrier guards WAR)
    fl_stage(Ks0, Vs0, K, Vt, kbase, vbase, 0, tid);
    __syncthreads();

    for (int kt = 0; kt <= qt; kt += 2) {
      if (kt + 1 <= qt) fl_stage(Ks1, Vs1, K, Vt, kbase, vbase, kt + 1, tid);
      fl_body(Ks0, Vs0, kt);
      __syncthreads();
      if (kt + 1 <= qt) {
        if (kt + 2 <= qt) fl_stage(Ks0, Vs0, K, Vt, kbase, vbase, kt + 2, tid);
        fl_body(Ks1, Vs1, kt + 1);
        __syncthreads();
      }
    }

    float inv[4];
    for (int r = 0; r < 4; ++r) inv[r] = 1.f / li[r];
    size_t obase = ((size_t)(b * 2048 + qt * 64 + wave * 16)) * 2048 + h * 128;
    for (int d = 0; d < 8; ++d)
      for (int r = 0; r < 4; ++r)
        O[obase + (size_t)(quad * 4 + r) * 2048 + d * 16 + l] = f2bf(Oacc[d][r] * inv[r]);
  }
}

// ---------------------------------------------------------------------------
extern "C" void kernel_launch(void* const* d_in, const int* in_sizes, int n_in,
                              void* d_out, int out_size, void* d_ws, size_t ws_size,
                              hipStream_t stream) {
  const void* X  = d_in[0];
  const void* Wq = d_in[3];
  const void* Wk = d_in[4];
  const void* Wv = d_in[5];
  const void* Wo = d_in[6];

  u16* base = (u16*)d_ws;
  int* flag = (int*)d_ws;
  const size_t TOK = 4096, DM = 2048;
  u16* Xbf = base + 128;               // 8M u16
  u16* Qw  = Xbf + TOK * DM;           // 8M
  u16* Kw  = Qw + TOK * DM;            // 8M
  u16* Vw  = Kw + TOK * DM;            // 8M (V, then attention output)
  u16* WT3 = Vw + TOK * DM;            // 12M u16: WqT ++ WkT ++ WvT (6144x2048)
  u16* Vtw = Xbf;                      // X dead after QKV gemm
  float* Wf = (float*)Xbf;             // f32 Wo-GEMM out: 33.5MB over Xbf+Qw+
                                       // head of Kw (all dead at Wo time)

  sniff_dtype<<<1, 256, 0, stream>>>((const unsigned*)X, flag);
  convert_x<<<4096, 256, 0, stream>>>(X, Xbf, flag);

  transpose_w<<<dim3(32, 32), 256, 0, stream>>>(Wq, WT3, flag);
  transpose_w<<<dim3(32, 32), 256, 0, stream>>>(Wk, WT3 + DM * DM, flag);
  transpose_w<<<dim3(32, 32), 256, 0, stream>>>(Wv, WT3 + 2 * DM * DM, flag);
  qkv_gemm<<<dim3(48, 32), 256, 0, stream>>>(Xbf, WT3, Qw, Kw, Vw);

  rope_k<<<dim3(512, 2), 256, 0, stream>>>(Qw, Kw);
  transpose_v<<<dim3(32, 2, 32), 256, 0, stream>>>(Vw, Vtw);
  flash_k<<<dim3(16, 16, 2), 256, 0, stream>>>(Qw, Kw, Vtw, Vw);

  transpose_w<<<dim3(32, 32), 256, 0, stream>>>(Wo, WT3, flag);
  gemm128_wo<<<dim3(16, 32), 256, 0, stream>>>(Vw, WT3, Wf);
  convert_out<<<8192, 256, 0, stream>>>(Wf, d_out, flag);
}

// Round 13
// 445.518 us; speedup vs baseline: 1.6056x; 1.0334x over previous
//
#include <hip/hip_runtime.h>
#include <hip/hip_bf16.h>

typedef unsigned short u16;
typedef __bf16 bf16x8 __attribute__((ext_vector_type(8)));
typedef float f32x4 __attribute__((ext_vector_type(4)));
typedef unsigned short u16x8 __attribute__((ext_vector_type(8)));
typedef unsigned short u16x4 __attribute__((ext_vector_type(4)));

__device__ __forceinline__ u16 f2bf(float f) {
  union { float f; unsigned u; } v; v.f = f;
  unsigned r = (v.u + 0x7FFFu + ((v.u >> 16) & 1u)) >> 16;
  return (u16)r;
}
__device__ __forceinline__ float bf2f(u16 s) {
  union { unsigned u; float f; } v; v.u = ((unsigned)s) << 16;
  return v.f;
}
__device__ __forceinline__ f32x4 zero4() { f32x4 z = {0.f, 0.f, 0.f, 0.f}; return z; }

__device__ __forceinline__ void async16(void* lds, const void* g) {
  __builtin_amdgcn_global_load_lds(
      (__attribute__((address_space(1))) void*)(void*)g,
      (__attribute__((address_space(3))) void*)lds, 16, 0, 0);
}

// Counted wait + barrier in ONE asm block ("memory" clobber = compiler fence:
// no ds_read may be hoisted above it; s_barrier publishes all waves' DMA).
// vmcnt(N): wait until <= N vm ops outstanding (m135-verified semantics).
#define WBAR(N) asm volatile("s_waitcnt vmcnt(" #N ")\n\ts_barrier" ::: "memory")

// ---------------------------------------------------------------------------
// Dtype sniff: 1 = f32 inputs, 0 = bf16 inputs. Deterministic.
// ---------------------------------------------------------------------------
__global__ void sniff_dtype(const unsigned* __restrict__ X, int* __restrict__ flag) {
  __shared__ int cnt;
  if (threadIdx.x == 0) cnt = 0;
  __syncthreads();
  unsigned w = X[(size_t)threadIdx.x * 16384 + 1000];
  int e = (int)((w >> 7) & 0xFF);
  if (e >= 100 && e <= 150) atomicAdd(&cnt, 1);
  __syncthreads();
  if (threadIdx.x == 0) flag[0] = (cnt < 192) ? 1 : 0;
}

// ---------------------------------------------------------------------------
// X ingest -> bf16.
// ---------------------------------------------------------------------------
__global__ __launch_bounds__(256) void convert_x(
    const void* __restrict__ X, u16* __restrict__ dst, const int* __restrict__ flag) {
  const int mode = flag[0];
  size_t i8 = ((size_t)blockIdx.x * 256 + threadIdx.x) * 8;
  if (mode) {
    const float4* f = (const float4*)X;
    float4 a = f[i8 / 4], b = f[i8 / 4 + 1];
    u16x8 o;
    o[0] = f2bf(a.x); o[1] = f2bf(a.y); o[2] = f2bf(a.z); o[3] = f2bf(a.w);
    o[4] = f2bf(b.x); o[5] = f2bf(b.y); o[6] = f2bf(b.z); o[7] = f2bf(b.w);
    *(u16x8*)&dst[i8] = o;
  } else {
    *(u16x8*)&dst[i8] = *(const u16x8*)&((const u16*)X)[i8];
  }
}

// ---------------------------------------------------------------------------
// Output convert: Wf (f32, workspace) -> d_out (f32 if mode else bf16).
// ---------------------------------------------------------------------------
__global__ __launch_bounds__(256) void convert_out(
    const float* __restrict__ src, void* __restrict__ dst, const int* __restrict__ flag) {
  const int mode = flag[0];
  size_t i4 = ((size_t)blockIdx.x * 256 + threadIdx.x) * 4;
  float4 v = *(const float4*)&src[i4];
  if (mode) {
    *(float4*)&((float*)dst)[i4] = v;
  } else {
    u16x4 o;
    o[0] = f2bf(v.x); o[1] = f2bf(v.y); o[2] = f2bf(v.z); o[3] = f2bf(v.w);
    *(u16x4*)&((u16*)dst)[i4] = o;
  }
}

// ---------------------------------------------------------------------------
// Weight transpose + convert: Wt[n][k] = bf16(W[k][n]), 2048x2048.
// ---------------------------------------------------------------------------
__global__ __launch_bounds__(256) void transpose_w(
    const void* __restrict__ src, u16* __restrict__ d, const int* __restrict__ flag)
{
  __shared__ u16 t[64][65];
  const int mode = flag[0];
  int r0 = blockIdx.y * 64, c0 = blockIdx.x * 64;
  int tid = threadIdx.x;
  for (int j = 0; j < 2; ++j) {
    int idx = tid + j * 256;
    int r = idx >> 3, c = (idx & 7) * 8;
    size_t base = (size_t)(r0 + r) * 2048 + c0 + c;
    if (mode) {
      const float4* f = (const float4*)src;
      float4 a = f[base / 4], b = f[base / 4 + 1];
      t[r][c + 0] = f2bf(a.x); t[r][c + 1] = f2bf(a.y);
      t[r][c + 2] = f2bf(a.z); t[r][c + 3] = f2bf(a.w);
      t[r][c + 4] = f2bf(b.x); t[r][c + 5] = f2bf(b.y);
      t[r][c + 6] = f2bf(b.z); t[r][c + 7] = f2bf(b.w);
    } else {
      u16x8 v = *(const u16x8*)&((const u16*)src)[base];
      for (int q = 0; q < 8; ++q) t[r][c + q] = v[q];
    }
  }
  __syncthreads();
  for (int j = 0; j < 2; ++j) {
    int idx = tid + j * 256;
    int c = idx >> 3, r = (idx & 7) * 8;
    u16x8 v;
    for (int q = 0; q < 8; ++q) v[q] = t[r + q][c];
    *(u16x8*)&d[(size_t)(c0 + c) * 2048 + r0 + r] = v;
  }
}

// ---------------------------------------------------------------------------
// V transpose: Vt[(b*16+h)][d][kv] = V[b*2048+kv][h*128+d]
// ---------------------------------------------------------------------------
__global__ __launch_bounds__(256) void transpose_v(
    const u16* __restrict__ V, u16* __restrict__ Vt)
{
  __shared__ u16 t[64][65];
  int bh = blockIdx.z;
  int b = bh >> 4, h = bh & 15;
  int kv0 = blockIdx.x * 64, d0 = blockIdx.y * 64;
  int tid = threadIdx.x;
  for (int j = 0; j < 2; ++j) {
    int idx = tid + j * 256;
    int r = idx >> 3, c = (idx & 7) * 8;
    u16x8 v = *(const u16x8*)&V[(size_t)(b * 2048 + kv0 + r) * 2048 + h * 128 + d0 + c];
    for (int q = 0; q < 8; ++q) t[r][c + q] = v[q];
  }
  __syncthreads();
  for (int j = 0; j < 2; ++j) {
    int idx = tid + j * 256;
    int c = idx >> 3, r = (idx & 7) * 8;
    u16x8 v;
    for (int q = 0; q < 8; ++q) v[q] = t[r + q][c];
    *(u16x8*)&Vt[((size_t)bh * 128 + d0 + c) * 2048 + kv0 + r] = v;
  }
}

// ---------------------------------------------------------------------------
// RoPE in-place on Q and K (bf16) — trig reused across 4 heads (round-8 win).
// ---------------------------------------------------------------------------
__global__ __launch_bounds__(256) void rope_k(u16* __restrict__ Qp, u16* __restrict__ Kp)
{
  int idx = blockIdx.x * 256 + threadIdx.x;   // [0, 131072)
  u16* X = blockIdx.y ? Kp : Qp;
  int i8 = (idx & 7) * 8;                     // 8 slots of 8 within half-dh 64
  int hq = (idx >> 3) & 3;                    // head quad 0..3
  int tok = idx >> 5;                         // 0..4095
  int pos = tok & 2047;

  float c8[8], s8[8];
  for (int j = 0; j < 8; ++j) {
    float fi = (float)(i8 + j);
    float invf = __expf(fi * -0.14391156831212787f);  // ln(10000)/64
    float th = (float)pos * invf;
    sincosf(th, &s8[j], &c8[j]);
  }

  for (int hh = 0; hh < 4; ++hh) {
    int h = hq * 4 + hh;
    size_t base = (size_t)tok * 2048 + h * 128 + i8;
    u16x8 a = *(const u16x8*)&X[base];
    u16x8 bv = *(const u16x8*)&X[base + 64];
    u16x8 ra, rb;
    for (int j = 0; j < 8; ++j) {
      float x1 = bf2f(a[j]), x2 = bf2f(bv[j]);
      ra[j] = f2bf(x1 * c8[j] - x2 * s8[j]);
      rb[j] = f2bf(x2 * c8[j] + x1 * s8[j]);
    }
    *(u16x8*)&X[base] = ra;
    *(u16x8*)&X[base + 64] = rb;
  }
}

// ---------------------------------------------------------------------------
// 128x128 GEMM compute (m97 fragment layout), shared by both GEMMs.
// ---------------------------------------------------------------------------
__device__ __forceinline__ void qkv_compute(
    const u16* As, const u16* Bs, f32x4 (&acc)[4][4],
    int wr, int wc, int quad, int l)
{
  bf16x8 af[4], bfr[4];
  for (int mt = 0; mt < 4; ++mt) {
    int row = wr * 64 + mt * 16 + l;
    int g = quad ^ ((row >> 1) & 3);
    af[mt] = *(const bf16x8*)&As[row * 32 + g * 8];
  }
  for (int nt = 0; nt < 4; ++nt) {
    int row = wc * 64 + nt * 16 + l;
    int g = quad ^ ((row >> 1) & 3);
    bfr[nt] = *(const bf16x8*)&Bs[row * 32 + g * 8];
  }
  for (int mt = 0; mt < 4; ++mt)
    for (int nt = 0; nt < 4; ++nt)
      acc[mt][nt] = __builtin_amdgcn_mfma_f32_16x16x32_bf16(af[mt], bfr[nt], acc[mt][nt], 0, 0, 0);
}

// ---------------------------------------------------------------------------
// ROUND-19 DELTA (both GEMMs): counted-vmcnt deep pipeline (T4-minimum).
//   Round-12 PMC: VALUBusy 44->24 as predicted but MfmaUtil stuck at 34.7 —
//   ~40% of issue idle. __syncthreads = vmcnt(0) drain kills the prefetch
//   every K-step (m97 structural ceiling). Escape per m218 (+38% counted vs
//   drain0): raw s_barrier + COUNTED vmcnt so loads stay in flight across
//   barriers. 4 buffer pairs (64 KB, 2 blocks/CU), x4-unrolled bodies
//   (compile-time buffer identity — round-1 lesson), depth-3 prefetch:
//   body t stages tile t+3. Per body: WBAR(8) [12 outstanding -> retire the
//   tile about to be read; barrier publishes all waves' DMA + WAR-guards the
//   stage target], stage, 16 MFMA. Tail peeled with vmcnt 8/8/4/0.
// ---------------------------------------------------------------------------
__global__ __launch_bounds__(256) void qkv_gemm(
    const u16* __restrict__ A, const u16* __restrict__ Bt,
    u16* __restrict__ Qw, u16* __restrict__ Kw, u16* __restrict__ Vw)
{
  __shared__ __align__(16) u16 As0[128 * 32], Bs0[128 * 32];
  __shared__ __align__(16) u16 As1[128 * 32], Bs1[128 * 32];
  __shared__ __align__(16) u16 As2[128 * 32], Bs2[128 * 32];
  __shared__ __align__(16) u16 As3[128 * 32], Bs3[128 * 32];
  const int N = 2048;
  const int tid = threadIdx.x;
  const int wave = tid >> 6, lane = tid & 63;
  const int quad = lane >> 4, l = lane & 15;
  const int wr = wave >> 1, wc = wave & 1;
  const int m0 = blockIdx.y * 128, n0full = blockIdx.x * 128;
  const int mat = n0full >> 11;
  const int n0 = n0full & 2047;
  u16* C = (mat == 0) ? Qw : ((mat == 1) ? Kw : Vw);

  f32x4 acc[4][4];
  for (int i = 0; i < 4; ++i)
    for (int j = 0; j < 4; ++j) acc[i][j] = zero4();

  const int rowA0 = tid >> 2;
  const int gA0 = (tid & 3) ^ ((rowA0 >> 1) & 3);
  const int rowA1 = (tid + 256) >> 2;
  const int gA1 = ((tid + 256) & 3) ^ ((rowA1 >> 1) & 3);

  const u16* pA0 = &A[(size_t)(m0 + rowA0) * 2048 + gA0 * 8];
  const u16* pA1 = &A[(size_t)(m0 + rowA1) * 2048 + gA1 * 8];
  const u16* pB0 = &Bt[(size_t)(n0full + rowA0) * 2048 + gA0 * 8];
  const u16* pB1 = &Bt[(size_t)(n0full + rowA1) * 2048 + gA1 * 8];

#define STG(AS, BS, OFF) \
  async16(&AS[tid * 8], pA0 + (OFF)); async16(&AS[(tid + 256) * 8], pA1 + (OFF)); \
  async16(&BS[tid * 8], pB0 + (OFF)); async16(&BS[(tid + 256) * 8], pB1 + (OFF));

  // prologue: stage tiles 0,1,2 (12 loads in flight)
  STG(As0, Bs0, 0)
  STG(As1, Bs1, 32)
  STG(As2, Bs2, 64)

  for (int g = 0; g < 15; ++g) {
    WBAR(8); STG(As3, Bs3, 96)  qkv_compute(As0, Bs0, acc, wr, wc, quad, l);
    WBAR(8); STG(As0, Bs0, 128) qkv_compute(As1, Bs1, acc, wr, wc, quad, l);
    WBAR(8); STG(As1, Bs1, 160) qkv_compute(As2, Bs2, acc, wr, wc, quad, l);
    WBAR(8); STG(As2, Bs2, 192) qkv_compute(As3, Bs3, acc, wr, wc, quad, l);
    pA0 += 128; pA1 += 128; pB0 += 128; pB1 += 128;
  }
  // peeled last group: bodies 60..63 (tile 63 staged in body 60)
  WBAR(8); STG(As3, Bs3, 96)  qkv_compute(As0, Bs0, acc, wr, wc, quad, l);
  WBAR(8); qkv_compute(As1, Bs1, acc, wr, wc, quad, l);
  WBAR(4); qkv_compute(As2, Bs2, acc, wr, wc, quad, l);
  WBAR(0); qkv_compute(As3, Bs3, acc, wr, wc, quad, l);
#undef STG

  for (int mt = 0; mt < 4; ++mt)
    for (int nt = 0; nt < 4; ++nt)
      for (int r = 0; r < 4; ++r) {
        int m = m0 + wr * 64 + mt * 16 + quad * 4 + r;
        int n = n0 + wc * 64 + nt * 16 + l;
        C[(size_t)m * N + n] = f2bf(acc[mt][nt][r]);
      }
}

// ---------------------------------------------------------------------------
// Wo GEMM — same counted-vmcnt pipeline; f32 output to WORKSPACE (clean
// write path — round-7 d_out anomaly stays routed around).
// ---------------------------------------------------------------------------
__global__ __launch_bounds__(256) void gemm128_wo(
    const u16* __restrict__ A, const u16* __restrict__ Bt, float* __restrict__ Wf)
{
  __shared__ __align__(16) u16 As0[128 * 32], Bs0[128 * 32];
  __shared__ __align__(16) u16 As1[128 * 32], Bs1[128 * 32];
  __shared__ __align__(16) u16 As2[128 * 32], Bs2[128 * 32];
  __shared__ __align__(16) u16 As3[128 * 32], Bs3[128 * 32];
  const int N = 2048;
  const int tid = threadIdx.x;
  const int wave = tid >> 6, lane = tid & 63;
  const int quad = lane >> 4, l = lane & 15;
  const int wr = wave >> 1, wc = wave & 1;
  const int m0 = blockIdx.y * 128, n0 = blockIdx.x * 128;

  f32x4 acc[4][4];
  for (int i = 0; i < 4; ++i)
    for (int j = 0; j < 4; ++j) acc[i][j] = zero4();

  const int rowA0 = tid >> 2;
  const int gA0 = (tid & 3) ^ ((rowA0 >> 1) & 3);
  const int rowA1 = (tid + 256) >> 2;
  const int gA1 = ((tid + 256) & 3) ^ ((rowA1 >> 1) & 3);

  const u16* pA0 = &A[(size_t)(m0 + rowA0) * 2048 + gA0 * 8];
  const u16* pA1 = &A[(size_t)(m0 + rowA1) * 2048 + gA1 * 8];
  const u16* pB0 = &Bt[(size_t)(n0 + rowA0) * 2048 + gA0 * 8];
  const u16* pB1 = &Bt[(size_t)(n0 + rowA1) * 2048 + gA1 * 8];

#define STG(AS, BS, OFF) \
  async16(&AS[tid * 8], pA0 + (OFF)); async16(&AS[(tid + 256) * 8], pA1 + (OFF)); \
  async16(&BS[tid * 8], pB0 + (OFF)); async16(&BS[(tid + 256) * 8], pB1 + (OFF));

  STG(As0, Bs0, 0)
  STG(As1, Bs1, 32)
  STG(As2, Bs2, 64)

  for (int g = 0; g < 15; ++g) {
    WBAR(8); STG(As3, Bs3, 96)  qkv_compute(As0, Bs0, acc, wr, wc, quad, l);
    WBAR(8); STG(As0, Bs0, 128) qkv_compute(As1, Bs1, acc, wr, wc, quad, l);
    WBAR(8); STG(As1, Bs1, 160) qkv_compute(As2, Bs2, acc, wr, wc, quad, l);
    WBAR(8); STG(As2, Bs2, 192) qkv_compute(As3, Bs3, acc, wr, wc, quad, l);
    pA0 += 128; pA1 += 128; pB0 += 128; pB1 += 128;
  }
  WBAR(8); STG(As3, Bs3, 96)  qkv_compute(As0, Bs0, acc, wr, wc, quad, l);
  WBAR(8); qkv_compute(As1, Bs1, acc, wr, wc, quad, l);
  WBAR(4); qkv_compute(As2, Bs2, acc, wr, wc, quad, l);
  WBAR(0); qkv_compute(As3, Bs3, acc, wr, wc, quad, l);
#undef STG

  for (int mt = 0; mt < 4; ++mt)
    for (int nt = 0; nt < 4; ++nt)
      for (int r = 0; r < 4; ++r) {
        int m = m0 + wr * 64 + mt * 16 + quad * 4 + r;
        int n = n0 + wc * 64 + nt * 16 + l;
        Wf[(size_t)m * N + n] = acc[mt][nt][r];
      }
}

// ---------------------------------------------------------------------------
// Flash attention, causal — unchanged (causal-paired balanced grid +
// depth-1 compile-time dbuf pipeline). Known-good.
// ---------------------------------------------------------------------------
__device__ __forceinline__ void fl_stage(
    u16* Ks, u16* Vs, const u16* K, const u16* Vt,
    size_t kbase, size_t vbase, int kt, int tid)
{
  for (int j = 0; j < 4; ++j) {
    int tf = tid + j * 256;
    int row = tf >> 4, p = tf & 15;
    int g = p ^ (row & 7);
    async16(&Ks[tf * 8], &K[kbase + (size_t)(kt * 64 + row) * 2048 + g * 8]);
  }
  for (int j = 0; j < 4; ++j) {
    int tf = tid + j * 256;
    int row = tf >> 3, p = tf & 7;
    int g = p ^ (row & 7);
    async16(&Vs[tf * 8], &Vt[vbase + (size_t)row * 2048 + kt * 64 + g * 8]);
  }
}

__global__ __launch_bounds__(256) void flash_k(
    const u16* __restrict__ Q, const u16* __restrict__ K,
    const u16* __restrict__ Vt, u16* __restrict__ O)
{
  __shared__ __align__(16) u16 Ks0[64 * 128];
  __shared__ __align__(16) u16 Vs0[128 * 64];
  __shared__ __align__(16) u16 Ks1[64 * 128];
  __shared__ __align__(16) u16 Vs1[128 * 64];
  __shared__ __align__(16) u16 Ps[4][16 * 64];

  const int tid = threadIdx.x;
  const int wave = tid >> 6, lane = tid & 63;
  const int quad = lane >> 4, l = lane & 15;
  const int pair = blockIdx.x;            // 0..15
  const int h = blockIdx.y, b = blockIdx.z;

  const size_t kbase = ((size_t)b * 2048) * 2048 + h * 128;
  const size_t vbase = ((size_t)(b * 16 + h)) * 128 * 2048;

  for (int half = 0; half < 2; ++half) {
    const int qt = half ? pair : (31 - pair);  // big tile first

    const size_t qoff = ((size_t)(b * 2048 + qt * 64)) * 2048 + h * 128;
    bf16x8 qf[4];
    for (int ks = 0; ks < 4; ++ks)
      qf[ks] = *(const bf16x8*)&Q[qoff + (size_t)(wave * 16 + l) * 2048 + (ks * 4 + quad) * 8];

    f32x4 Oacc[8];
    for (int i = 0; i < 8; ++i) Oacc[i] = zero4();
    float mi[4] = {-3e38f, -3e38f, -3e38f, -3e38f};
    float li[4] = {0.f, 0.f, 0.f, 0.f};

    auto fl_body = [&](const u16* Ksb, const u16* Vsb, int kt) {
      f32x4 S[4];
      for (int nt = 0; nt < 4; ++nt) S[nt] = zero4();
      for (int ks = 0; ks < 4; ++ks) {
        int g = ks * 4 + quad;
        for (int nt = 0; nt < 4; ++nt) {
          bf16x8 bk = *(const bf16x8*)&Ksb[(nt * 16 + l) * 128 + (g ^ (l & 7)) * 8];
          S[nt] = __builtin_amdgcn_mfma_f32_16x16x32_bf16(qf[ks], bk, S[nt], 0, 0, 0);
        }
      }

      const bool dg = (kt == qt);
      float Pv[4][4];
      float rm[4] = {-3e38f, -3e38f, -3e38f, -3e38f};
      for (int nt = 0; nt < 4; ++nt)
        for (int r = 0; r < 4; ++r) {
          float s = S[nt][r] * 0.08838834764831845f;  // 1/sqrt(128)
          if (dg && (nt * 16 + l > wave * 16 + quad * 4 + r)) s = -3e38f;
          Pv[nt][r] = s;
          rm[r] = fmaxf(rm[r], s);
        }
      for (int r = 0; r < 4; ++r)
        for (int off = 1; off < 16; off <<= 1)
          rm[r] = fmaxf(rm[r], __shfl_xor(rm[r], off));
      float al[4], rs[4];
      for (int r = 0; r < 4; ++r) {
        float mn = fmaxf(mi[r], rm[r]);
        al[r] = __expf(mi[r] - mn);
        mi[r] = mn;
        rs[r] = 0.f;
      }
      for (int nt = 0; nt < 4; ++nt)
        for (int r = 0; r < 4; ++r) {
          float p = __expf(Pv[nt][r] - mi[r]);
          Pv[nt][r] = p;
          rs[r] += p;
        }
      for (int r = 0; r < 4; ++r) {
        for (int off = 1; off < 16; off <<= 1)
          rs[r] += __shfl_xor(rs[r], off);
        li[r] = li[r] * al[r] + rs[r];
      }
      for (int nt = 0; nt < 4; ++nt) {
        int gc = nt * 2 + (l >> 3);
        for (int r = 0; r < 4; ++r) {
          int row = quad * 4 + r;
          Ps[wave][row * 64 + ((gc ^ (row & 7)) * 8) + (l & 7)] = f2bf(Pv[nt][r]);
        }
      }
      for (int d = 0; d < 8; ++d)
        for (int r = 0; r < 4; ++r) Oacc[d][r] *= al[r];
      for (int ks = 0; ks < 2; ++ks) {
        int g = ks * 4 + quad;
        bf16x8 ap = *(const bf16x8*)&Ps[wave][l * 64 + (g ^ (l & 7)) * 8];
        for (int d = 0; d < 8; ++d) {
          bf16x8 bv = *(const bf16x8*)&Vsb[(d * 16 + l) * 64 + (g ^ (l & 7)) * 8];
          Oacc[d] = __builtin_amdgcn_mfma_f32_16x16x32_bf16(ap, bv, Oacc[d], 0, 0, 0);
        }
      }
    };

    // prologue: stage kt=0 into buf0 (prev half's end barrier guards WAR)
    fl_stage(Ks0, Vs0, K, Vt, kbase, vbase, 0, tid);
    __syncthreads();

    for (int kt = 0; kt <= qt; kt += 2) {
      if (kt + 1 <= qt) fl_stage(Ks1, Vs1, K, Vt, kbase, vbase, kt + 1, tid);
      fl_body(Ks0, Vs0, kt);
      __syncthreads();
      if (kt + 1 <= qt) {
        if (kt + 2 <= qt) fl_stage(Ks0, Vs0, K, Vt, kbase, vbase, kt + 2, tid);
        fl_body(Ks1, Vs1, kt + 1);
        __syncthreads();
      }
    }

    float inv[4];
    for (int r = 0; r < 4; ++r) inv[r] = 1.f / li[r];
    size_t obase = ((size_t)(b * 2048 + qt * 64 + wave * 16)) * 2048 + h * 128;
    for (int d = 0; d < 8; ++d)
      for (int r = 0; r < 4; ++r)
        O[obase + (size_t)(quad * 4 + r) * 2048 + d * 16 + l] = f2bf(Oacc[d][r] * inv[r]);
  }
}

// ---------------------------------------------------------------------------
extern "C" void kernel_launch(void* const* d_in, const int* in_sizes, int n_in,
                              void* d_out, int out_size, void* d_ws, size_t ws_size,
                              hipStream_t stream) {
  const void* X  = d_in[0];
  const void* Wq = d_in[3];
  const void* Wk = d_in[4];
  const void* Wv = d_in[5];
  const void* Wo = d_in[6];

  u16* base = (u16*)d_ws;
  int* flag = (int*)d_ws;
  const size_t TOK = 4096, DM = 2048;
  u16* Xbf = base + 128;               // 8M u16
  u16* Qw  = Xbf + TOK * DM;           // 8M
  u16* Kw  = Qw + TOK * DM;            // 8M
  u16* Vw  = Kw + TOK * DM;            // 8M (V, then attention output)
  u16* WT3 = Vw + TOK * DM;            // 12M u16: WqT ++ WkT ++ WvT (6144x2048)
  u16* Vtw = Xbf;                      // X dead after QKV gemm
  float* Wf = (float*)Xbf;             // f32 Wo-GEMM out: 33.5MB over Xbf+Qw+
                                       // head of Kw (all dead at Wo time)

  sniff_dtype<<<1, 256, 0, stream>>>((const unsigned*)X, flag);
  convert_x<<<4096, 256, 0, stream>>>(X, Xbf, flag);

  transpose_w<<<dim3(32, 32), 256, 0, stream>>>(Wq, WT3, flag);
  transpose_w<<<dim3(32, 32), 256, 0, stream>>>(Wk, WT3 + DM * DM, flag);
  transpose_w<<<dim3(32, 32), 256, 0, stream>>>(Wv, WT3 + 2 * DM * DM, flag);
  qkv_gemm<<<dim3(48, 32), 256, 0, stream>>>(Xbf, WT3, Qw, Kw, Vw);

  rope_k<<<dim3(512, 2), 256, 0, stream>>>(Qw, Kw);
  transpose_v<<<dim3(32, 2, 32), 256, 0, stream>>>(Vw, Vtw);
  flash_k<<<dim3(16, 16, 2), 256, 0, stream>>>(Qw, Kw, Vtw, Vw);

  transpose_w<<<dim3(32, 32), 256, 0, stream>>>(Wo, WT3, flag);
  gemm128_wo<<<dim3(16, 32), 256, 0, stream>>>(Vw, WT3, Wf);
  convert_out<<<8192, 256, 0, stream>>>(Wf, d_out, flag);
}

// Round 14
// 437.100 us; speedup vs baseline: 1.6365x; 1.0193x over previous
//
#include <hip/hip_runtime.h>
#include <hip/hip_bf16.h>

typedef unsigned short u16;
typedef __bf16 bf16x8 __attribute__((ext_vector_type(8)));
typedef float f32x4 __attribute__((ext_vector_type(4)));
typedef unsigned short u16x8 __attribute__((ext_vector_type(8)));
typedef unsigned short u16x4 __attribute__((ext_vector_type(4)));

__device__ __forceinline__ u16 f2bf(float f) {
  union { float f; unsigned u; } v; v.f = f;
  unsigned r = (v.u + 0x7FFFu + ((v.u >> 16) & 1u)) >> 16;
  return (u16)r;
}
__device__ __forceinline__ float bf2f(u16 s) {
  union { unsigned u; float f; } v; v.u = ((unsigned)s) << 16;
  return v.f;
}
__device__ __forceinline__ f32x4 zero4() { f32x4 z = {0.f, 0.f, 0.f, 0.f}; return z; }

__device__ __forceinline__ void async16(void* lds, const void* g) {
  __builtin_amdgcn_global_load_lds(
      (__attribute__((address_space(1))) void*)(void*)g,
      (__attribute__((address_space(3))) void*)lds, 16, 0, 0);
}

// Counted wait + barrier in ONE asm block ("memory" clobber = compiler fence).
#define WBAR(N) asm volatile("s_waitcnt vmcnt(" #N ")\n\ts_barrier" ::: "memory")

// ---------------------------------------------------------------------------
// Dtype sniff: 1 = f32 inputs, 0 = bf16 inputs. Deterministic.
// ---------------------------------------------------------------------------
__global__ void sniff_dtype(const unsigned* __restrict__ X, int* __restrict__ flag) {
  __shared__ int cnt;
  if (threadIdx.x == 0) cnt = 0;
  __syncthreads();
  unsigned w = X[(size_t)threadIdx.x * 16384 + 1000];
  int e = (int)((w >> 7) & 0xFF);
  if (e >= 100 && e <= 150) atomicAdd(&cnt, 1);
  __syncthreads();
  if (threadIdx.x == 0) flag[0] = (cnt < 192) ? 1 : 0;
}

// ---------------------------------------------------------------------------
// X ingest -> bf16.
// ---------------------------------------------------------------------------
__global__ __launch_bounds__(256) void convert_x(
    const void* __restrict__ X, u16* __restrict__ dst, const int* __restrict__ flag) {
  const int mode = flag[0];
  size_t i8 = ((size_t)blockIdx.x * 256 + threadIdx.x) * 8;
  if (mode) {
    const float4* f = (const float4*)X;
    float4 a = f[i8 / 4], b = f[i8 / 4 + 1];
    u16x8 o;
    o[0] = f2bf(a.x); o[1] = f2bf(a.y); o[2] = f2bf(a.z); o[3] = f2bf(a.w);
    o[4] = f2bf(b.x); o[5] = f2bf(b.y); o[6] = f2bf(b.z); o[7] = f2bf(b.w);
    *(u16x8*)&dst[i8] = o;
  } else {
    *(u16x8*)&dst[i8] = *(const u16x8*)&((const u16*)X)[i8];
  }
}

// ---------------------------------------------------------------------------
// Output convert: Wf (f32, workspace) -> d_out (f32 if mode else bf16).
// ---------------------------------------------------------------------------
__global__ __launch_bounds__(256) void convert_out(
    const float* __restrict__ src, void* __restrict__ dst, const int* __restrict__ flag) {
  const int mode = flag[0];
  size_t i4 = ((size_t)blockIdx.x * 256 + threadIdx.x) * 4;
  float4 v = *(const float4*)&src[i4];
  if (mode) {
    *(float4*)&((float*)dst)[i4] = v;
  } else {
    u16x4 o;
    o[0] = f2bf(v.x); o[1] = f2bf(v.y); o[2] = f2bf(v.z); o[3] = f2bf(v.w);
    *(u16x4*)&((u16*)dst)[i4] = o;
  }
}

// ---------------------------------------------------------------------------
// ROUND-20 DELTA: launch fusion (12 -> 8 launches). Budget reconstruction
// shows ~100 µs of wall time unaccounted by kernel-time arithmetic ->
// suspected per-launch gap overhead (~7-8 µs each). Fusions:
//   transpose_w3: Wq/Wk/Wv transposes in one launch (z picks source).
//   mid_fused:    rope + transpose_v + transpose_w(Wo) in one launch
//                 (independent phases, block-exclusive branches).
// All compute bodies byte-identical to round-13 passing code.
// ---------------------------------------------------------------------------
__global__ __launch_bounds__(256) void transpose_w3(
    const void* __restrict__ W0, const void* __restrict__ W1,
    const void* __restrict__ W2, u16* __restrict__ dbase,
    const int* __restrict__ flag)
{
  __shared__ u16 t[64][65];
  const void* src = (blockIdx.z == 0) ? W0 : (blockIdx.z == 1) ? W1 : W2;
  u16* d = dbase + (size_t)blockIdx.z * 2048 * 2048;
  const int mode = flag[0];
  int r0 = blockIdx.y * 64, c0 = blockIdx.x * 64;
  int tid = threadIdx.x;
  for (int j = 0; j < 2; ++j) {
    int idx = tid + j * 256;
    int r = idx >> 3, c = (idx & 7) * 8;
    size_t base = (size_t)(r0 + r) * 2048 + c0 + c;
    if (mode) {
      const float4* f = (const float4*)src;
      float4 a = f[base / 4], b = f[base / 4 + 1];
      t[r][c + 0] = f2bf(a.x); t[r][c + 1] = f2bf(a.y);
      t[r][c + 2] = f2bf(a.z); t[r][c + 3] = f2bf(a.w);
      t[r][c + 4] = f2bf(b.x); t[r][c + 5] = f2bf(b.y);
      t[r][c + 6] = f2bf(b.z); t[r][c + 7] = f2bf(b.w);
    } else {
      u16x8 v = *(const u16x8*)&((const u16*)src)[base];
      for (int q = 0; q < 8; ++q) t[r][c + q] = v[q];
    }
  }
  __syncthreads();
  for (int j = 0; j < 2; ++j) {
    int idx = tid + j * 256;
    int c = idx >> 3, r = (idx & 7) * 8;
    u16x8 v;
    for (int q = 0; q < 8; ++q) v[q] = t[r + q][c];
    *(u16x8*)&d[(size_t)(c0 + c) * 2048 + r0 + r] = v;
  }
}

// mid_fused: blocks [0,1024) rope Q/K; [1024,3072) transpose_v;
// [3072,4096) transpose_w(Wo). All independent; WT3 dead after qkv_gemm.
__global__ __launch_bounds__(256) void mid_fused(
    u16* __restrict__ Qp, u16* __restrict__ Kp,
    const u16* __restrict__ V, u16* __restrict__ Vt,
    const void* __restrict__ Wo, u16* __restrict__ WT,
    const int* __restrict__ flag)
{
  __shared__ u16 t[64][65];
  const int tid = threadIdx.x;
  const int blk = blockIdx.x;

  if (blk < 1024) {
    // ---- RoPE (trig reused across 4 heads) ----
    int y = blk >> 9;                 // 0: Q, 1: K
    int bx = blk & 511;
    u16* X = y ? Kp : Qp;
    int idx = bx * 256 + tid;         // [0, 131072)
    int i8 = (idx & 7) * 8;
    int hq = (idx >> 3) & 3;
    int tok = idx >> 5;
    int pos = tok & 2047;

    float c8[8], s8[8];
    for (int j = 0; j < 8; ++j) {
      float fi = (float)(i8 + j);
      float invf = __expf(fi * -0.14391156831212787f);  // ln(10000)/64
      float th = (float)pos * invf;
      sincosf(th, &s8[j], &c8[j]);
    }
    for (int hh = 0; hh < 4; ++hh) {
      int h = hq * 4 + hh;
      size_t base = (size_t)tok * 2048 + h * 128 + i8;
      u16x8 a = *(const u16x8*)&X[base];
      u16x8 bv = *(const u16x8*)&X[base + 64];
      u16x8 ra, rb;
      for (int j = 0; j < 8; ++j) {
        float x1 = bf2f(a[j]), x2 = bf2f(bv[j]);
        ra[j] = f2bf(x1 * c8[j] - x2 * s8[j]);
        rb[j] = f2bf(x2 * c8[j] + x1 * s8[j]);
      }
      *(u16x8*)&X[base] = ra;
      *(u16x8*)&X[base + 64] = rb;
    }
  } else if (blk < 3072) {
    // ---- V transpose: Vt[(b*16+h)][d][kv] = V[b*2048+kv][h*128+d] ----
    int tvb = blk - 1024;
    int bx = tvb & 31, by = (tvb >> 5) & 1, bz = tvb >> 6;
    int b = bz >> 4, h = bz & 15;
    int kv0 = bx * 64, d0 = by * 64;
    for (int j = 0; j < 2; ++j) {
      int idx = tid + j * 256;
      int r = idx >> 3, c = (idx & 7) * 8;
      u16x8 v = *(const u16x8*)&V[(size_t)(b * 2048 + kv0 + r) * 2048 + h * 128 + d0 + c];
      for (int q = 0; q < 8; ++q) t[r][c + q] = v[q];
    }
    __syncthreads();
    for (int j = 0; j < 2; ++j) {
      int idx = tid + j * 256;
      int c = idx >> 3, r = (idx & 7) * 8;
      u16x8 v;
      for (int q = 0; q < 8; ++q) v[q] = t[r + q][c];
      *(u16x8*)&Vt[((size_t)bz * 128 + d0 + c) * 2048 + kv0 + r] = v;
    }
  } else {
    // ---- Wo transpose + convert ----
    int twb = blk - 3072;
    int c0 = (twb & 31) * 64, r0 = (twb >> 5) * 64;
    const int mode = flag[0];
    for (int j = 0; j < 2; ++j) {
      int idx = tid + j * 256;
      int r = idx >> 3, c = (idx & 7) * 8;
      size_t base = (size_t)(r0 + r) * 2048 + c0 + c;
      if (mode) {
        const float4* f = (const float4*)Wo;
        float4 a = f[base / 4], b2 = f[base / 4 + 1];
        t[r][c + 0] = f2bf(a.x); t[r][c + 1] = f2bf(a.y);
        t[r][c + 2] = f2bf(a.z); t[r][c + 3] = f2bf(a.w);
        t[r][c + 4] = f2bf(b2.x); t[r][c + 5] = f2bf(b2.y);
        t[r][c + 6] = f2bf(b2.z); t[r][c + 7] = f2bf(b2.w);
      } else {
        u16x8 v = *(const u16x8*)&((const u16*)Wo)[base];
        for (int q = 0; q < 8; ++q) t[r][c + q] = v[q];
      }
    }
    __syncthreads();
    for (int j = 0; j < 2; ++j) {
      int idx = tid + j * 256;
      int c = idx >> 3, r = (idx & 7) * 8;
      u16x8 v;
      for (int q = 0; q < 8; ++q) v[q] = t[r + q][c];
      *(u16x8*)&WT[(size_t)(c0 + c) * 2048 + r0 + r] = v;
    }
  }
}

// ---------------------------------------------------------------------------
// 128x128 GEMM compute (m97 fragment layout), shared by both GEMMs.
// ---------------------------------------------------------------------------
__device__ __forceinline__ void qkv_compute(
    const u16* As, const u16* Bs, f32x4 (&acc)[4][4],
    int wr, int wc, int quad, int l)
{
  bf16x8 af[4], bfr[4];
  for (int mt = 0; mt < 4; ++mt) {
    int row = wr * 64 + mt * 16 + l;
    int g = quad ^ ((row >> 1) & 3);
    af[mt] = *(const bf16x8*)&As[row * 32 + g * 8];
  }
  for (int nt = 0; nt < 4; ++nt) {
    int row = wc * 64 + nt * 16 + l;
    int g = quad ^ ((row >> 1) & 3);
    bfr[nt] = *(const bf16x8*)&Bs[row * 32 + g * 8];
  }
  for (int mt = 0; mt < 4; ++mt)
    for (int nt = 0; nt < 4; ++nt)
      acc[mt][nt] = __builtin_amdgcn_mfma_f32_16x16x32_bf16(af[mt], bfr[nt], acc[mt][nt], 0, 0, 0);
}

// ---------------------------------------------------------------------------
// Fused QKV GEMM — counted-vmcnt deep pipeline (round-13, known-passing).
// ---------------------------------------------------------------------------
__global__ __launch_bounds__(256) void qkv_gemm(
    const u16* __restrict__ A, const u16* __restrict__ Bt,
    u16* __restrict__ Qw, u16* __restrict__ Kw, u16* __restrict__ Vw)
{
  __shared__ __align__(16) u16 As0[128 * 32], Bs0[128 * 32];
  __shared__ __align__(16) u16 As1[128 * 32], Bs1[128 * 32];
  __shared__ __align__(16) u16 As2[128 * 32], Bs2[128 * 32];
  __shared__ __align__(16) u16 As3[128 * 32], Bs3[128 * 32];
  const int N = 2048;
  const int tid = threadIdx.x;
  const int wave = tid >> 6, lane = tid & 63;
  const int quad = lane >> 4, l = lane & 15;
  const int wr = wave >> 1, wc = wave & 1;
  const int m0 = blockIdx.y * 128, n0full = blockIdx.x * 128;
  const int mat = n0full >> 11;
  const int n0 = n0full & 2047;
  u16* C = (mat == 0) ? Qw : ((mat == 1) ? Kw : Vw);

  f32x4 acc[4][4];
  for (int i = 0; i < 4; ++i)
    for (int j = 0; j < 4; ++j) acc[i][j] = zero4();

  const int rowA0 = tid >> 2;
  const int gA0 = (tid & 3) ^ ((rowA0 >> 1) & 3);
  const int rowA1 = (tid + 256) >> 2;
  const int gA1 = ((tid + 256) & 3) ^ ((rowA1 >> 1) & 3);

  const u16* pA0 = &A[(size_t)(m0 + rowA0) * 2048 + gA0 * 8];
  const u16* pA1 = &A[(size_t)(m0 + rowA1) * 2048 + gA1 * 8];
  const u16* pB0 = &Bt[(size_t)(n0full + rowA0) * 2048 + gA0 * 8];
  const u16* pB1 = &Bt[(size_t)(n0full + rowA1) * 2048 + gA1 * 8];

#define STG(AS, BS, OFF) \
  async16(&AS[tid * 8], pA0 + (OFF)); async16(&AS[(tid + 256) * 8], pA1 + (OFF)); \
  async16(&BS[tid * 8], pB0 + (OFF)); async16(&BS[(tid + 256) * 8], pB1 + (OFF));

  STG(As0, Bs0, 0)
  STG(As1, Bs1, 32)
  STG(As2, Bs2, 64)

  for (int g = 0; g < 15; ++g) {
    WBAR(8); STG(As3, Bs3, 96)  qkv_compute(As0, Bs0, acc, wr, wc, quad, l);
    WBAR(8); STG(As0, Bs0, 128) qkv_compute(As1, Bs1, acc, wr, wc, quad, l);
    WBAR(8); STG(As1, Bs1, 160) qkv_compute(As2, Bs2, acc, wr, wc, quad, l);
    WBAR(8); STG(As2, Bs2, 192) qkv_compute(As3, Bs3, acc, wr, wc, quad, l);
    pA0 += 128; pA1 += 128; pB0 += 128; pB1 += 128;
  }
  WBAR(8); STG(As3, Bs3, 96)  qkv_compute(As0, Bs0, acc, wr, wc, quad, l);
  WBAR(8); qkv_compute(As1, Bs1, acc, wr, wc, quad, l);
  WBAR(4); qkv_compute(As2, Bs2, acc, wr, wc, quad, l);
  WBAR(0); qkv_compute(As3, Bs3, acc, wr, wc, quad, l);
#undef STG

  for (int mt = 0; mt < 4; ++mt)
    for (int nt = 0; nt < 4; ++nt)
      for (int r = 0; r < 4; ++r) {
        int m = m0 + wr * 64 + mt * 16 + quad * 4 + r;
        int n = n0 + wc * 64 + nt * 16 + l;
        C[(size_t)m * N + n] = f2bf(acc[mt][nt][r]);
      }
}

// ---------------------------------------------------------------------------
// Wo GEMM — counted-vmcnt pipeline; f32 output to WORKSPACE (clean write
// path — round-7 d_out anomaly stays routed around).
// ---------------------------------------------------------------------------
__global__ __launch_bounds__(256) void gemm128_wo(
    const u16* __restrict__ A, const u16* __restrict__ Bt, float* __restrict__ Wf)
{
  __shared__ __align__(16) u16 As0[128 * 32], Bs0[128 * 32];
  __shared__ __align__(16) u16 As1[128 * 32], Bs1[128 * 32];
  __shared__ __align__(16) u16 As2[128 * 32], Bs2[128 * 32];
  __shared__ __align__(16) u16 As3[128 * 32], Bs3[128 * 32];
  const int N = 2048;
  const int tid = threadIdx.x;
  const int wave = tid >> 6, lane = tid & 63;
  const int quad = lane >> 4, l = lane & 15;
  const int wr = wave >> 1, wc = wave & 1;
  const int m0 = blockIdx.y * 128, n0 = blockIdx.x * 128;

  f32x4 acc[4][4];
  for (int i = 0; i < 4; ++i)
    for (int j = 0; j < 4; ++j) acc[i][j] = zero4();

  const int rowA0 = tid >> 2;
  const int gA0 = (tid & 3) ^ ((rowA0 >> 1) & 3);
  const int rowA1 = (tid + 256) >> 2;
  const int gA1 = ((tid + 256) & 3) ^ ((rowA1 >> 1) & 3);

  const u16* pA0 = &A[(size_t)(m0 + rowA0) * 2048 + gA0 * 8];
  const u16* pA1 = &A[(size_t)(m0 + rowA1) * 2048 + gA1 * 8];
  const u16* pB0 = &Bt[(size_t)(n0 + rowA0) * 2048 + gA0 * 8];
  const u16* pB1 = &Bt[(size_t)(n0 + rowA1) * 2048 + gA1 * 8];

#define STG(AS, BS, OFF) \
  async16(&AS[tid * 8], pA0 + (OFF)); async16(&AS[(tid + 256) * 8], pA1 + (OFF)); \
  async16(&BS[tid * 8], pB0 + (OFF)); async16(&BS[(tid + 256) * 8], pB1 + (OFF));

  STG(As0, Bs0, 0)
  STG(As1, Bs1, 32)
  STG(As2, Bs2, 64)

  for (int g = 0; g < 15; ++g) {
    WBAR(8); STG(As3, Bs3, 96)  qkv_compute(As0, Bs0, acc, wr, wc, quad, l);
    WBAR(8); STG(As0, Bs0, 128) qkv_compute(As1, Bs1, acc, wr, wc, quad, l);
    WBAR(8); STG(As1, Bs1, 160) qkv_compute(As2, Bs2, acc, wr, wc, quad, l);
    WBAR(8); STG(As2, Bs2, 192) qkv_compute(As3, Bs3, acc, wr, wc, quad, l);
    pA0 += 128; pA1 += 128; pB0 += 128; pB1 += 128;
  }
  WBAR(8); STG(As3, Bs3, 96)  qkv_compute(As0, Bs0, acc, wr, wc, quad, l);
  WBAR(8); qkv_compute(As1, Bs1, acc, wr, wc, quad, l);
  WBAR(4); qkv_compute(As2, Bs2, acc, wr, wc, quad, l);
  WBAR(0); qkv_compute(As3, Bs3, acc, wr, wc, quad, l);
#undef STG

  for (int mt = 0; mt < 4; ++mt)
    for (int nt = 0; nt < 4; ++nt)
      for (int r = 0; r < 4; ++r) {
        int m = m0 + wr * 64 + mt * 16 + quad * 4 + r;
        int n = n0 + wc * 64 + nt * 16 + l;
        Wf[(size_t)m * N + n] = acc[mt][nt][r];
      }
}

// ---------------------------------------------------------------------------
// Flash attention, causal — unchanged (causal-paired balanced grid +
// depth-1 compile-time dbuf pipeline). Known-good.
// ---------------------------------------------------------------------------
__device__ __forceinline__ void fl_stage(
    u16* Ks, u16* Vs, const u16* K, const u16* Vt,
    size_t kbase, size_t vbase, int kt, int tid)
{
  for (int j = 0; j < 4; ++j) {
    int tf = tid + j * 256;
    int row = tf >> 4, p = tf & 15;
    int g = p ^ (row & 7);
    async16(&Ks[tf * 8], &K[kbase + (size_t)(kt * 64 + row) * 2048 + g * 8]);
  }
  for (int j = 0; j < 4; ++j) {
    int tf = tid + j * 256;
    int row = tf >> 3, p = tf & 7;
    int g = p ^ (row & 7);
    async16(&Vs[tf * 8], &Vt[vbase + (size_t)row * 2048 + kt * 64 + g * 8]);
  }
}

__global__ __launch_bounds__(256) void flash_k(
    const u16* __restrict__ Q, const u16* __restrict__ K,
    const u16* __restrict__ Vt, u16* __restrict__ O)
{
  __shared__ __align__(16) u16 Ks0[64 * 128];
  __shared__ __align__(16) u16 Vs0[128 * 64];
  __shared__ __align__(16) u16 Ks1[64 * 128];
  __shared__ __align__(16) u16 Vs1[128 * 64];
  __shared__ __align__(16) u16 Ps[4][16 * 64];

  const int tid = threadIdx.x;
  const int wave = tid >> 6, lane = tid & 63;
  const int quad = lane >> 4, l = lane & 15;
  const int pair = blockIdx.x;            // 0..15
  const int h = blockIdx.y, b = blockIdx.z;

  const size_t kbase = ((size_t)b * 2048) * 2048 + h * 128;
  const size_t vbase = ((size_t)(b * 16 + h)) * 128 * 2048;

  for (int half = 0; half < 2; ++half) {
    const int qt = half ? pair : (31 - pair);  // big tile first

    const size_t qoff = ((size_t)(b * 2048 + qt * 64)) * 2048 + h * 128;
    bf16x8 qf[4];
    for (int ks = 0; ks < 4; ++ks)
      qf[ks] = *(const bf16x8*)&Q[qoff + (size_t)(wave * 16 + l) * 2048 + (ks * 4 + quad) * 8];

    f32x4 Oacc[8];
    for (int i = 0; i < 8; ++i) Oacc[i] = zero4();
    float mi[4] = {-3e38f, -3e38f, -3e38f, -3e38f};
    float li[4] = {0.f, 0.f, 0.f, 0.f};

    auto fl_body = [&](const u16* Ksb, const u16* Vsb, int kt) {
      f32x4 S[4];
      for (int nt = 0; nt < 4; ++nt) S[nt] = zero4();
      for (int ks = 0; ks < 4; ++ks) {
        int g = ks * 4 + quad;
        for (int nt = 0; nt < 4; ++nt) {
          bf16x8 bk = *(const bf16x8*)&Ksb[(nt * 16 + l) * 128 + (g ^ (l & 7)) * 8];
          S[nt] = __builtin_amdgcn_mfma_f32_16x16x32_bf16(qf[ks], bk, S[nt], 0, 0, 0);
        }
      }

      const bool dg = (kt == qt);
      float Pv[4][4];
      float rm[4] = {-3e38f, -3e38f, -3e38f, -3e38f};
      for (int nt = 0; nt < 4; ++nt)
        for (int r = 0; r < 4; ++r) {
          float s = S[nt][r] * 0.08838834764831845f;  // 1/sqrt(128)
          if (dg && (nt * 16 + l > wave * 16 + quad * 4 + r)) s = -3e38f;
          Pv[nt][r] = s;
          rm[r] = fmaxf(rm[r], s);
        }
      for (int r = 0; r < 4; ++r)
        for (int off = 1; off < 16; off <<= 1)
          rm[r] = fmaxf(rm[r], __shfl_xor(rm[r], off));
      float al[4], rs[4];
      for (int r = 0; r < 4; ++r) {
        float mn = fmaxf(mi[r], rm[r]);
        al[r] = __expf(mi[r] - mn);
        mi[r] = mn;
        rs[r] = 0.f;
      }
      for (int nt = 0; nt < 4; ++nt)
        for (int r = 0; r < 4; ++r) {
          float p = __expf(Pv[nt][r] - mi[r]);
          Pv[nt][r] = p;
          rs[r] += p;
        }
      for (int r = 0; r < 4; ++r) {
        for (int off = 1; off < 16; off <<= 1)
          rs[r] += __shfl_xor(rs[r], off);
        li[r] = li[r] * al[r] + rs[r];
      }
      for (int nt = 0; nt < 4; ++nt) {
        int gc = nt * 2 + (l >> 3);
        for (int r = 0; r < 4; ++r) {
          int row = quad * 4 + r;
          Ps[wave][row * 64 + ((gc ^ (row & 7)) * 8) + (l & 7)] = f2bf(Pv[nt][r]);
        }
      }
      for (int d = 0; d < 8; ++d)
        for (int r = 0; r < 4; ++r) Oacc[d][r] *= al[r];
      for (int ks = 0; ks < 2; ++ks) {
        int g = ks * 4 + quad;
        bf16x8 ap = *(const bf16x8*)&Ps[wave][l * 64 + (g ^ (l & 7)) * 8];
        for (int d = 0; d < 8; ++d) {
          bf16x8 bv = *(const bf16x8*)&Vsb[(d * 16 + l) * 64 + (g ^ (l & 7)) * 8];
          Oacc[d] = __builtin_amdgcn_mfma_f32_16x16x32_bf16(ap, bv, Oacc[d], 0, 0, 0);
        }
      }
    };

    // prologue: stage kt=0 into buf0 (prev half's end barrier guards WAR)
    fl_stage(Ks0, Vs0, K, Vt, kbase, vbase, 0, tid);
    __syncthreads();

    for (int kt = 0; kt <= qt; kt += 2) {
      if (kt + 1 <= qt) fl_stage(Ks1, Vs1, K, Vt, kbase, vbase, kt + 1, tid);
      fl_body(Ks0, Vs0, kt);
      __syncthreads();
      if (kt + 1 <= qt) {
        if (kt + 2 <= qt) fl_stage(Ks0, Vs0, K, Vt, kbase, vbase, kt + 2, tid);
        fl_body(Ks1, Vs1, kt + 1);
        __syncthreads();
      }
    }

    float inv[4];
    for (int r = 0; r < 4; ++r) inv[r] = 1.f / li[r];
    size_t obase = ((size_t)(b * 2048 + qt * 64 + wave * 16)) * 2048 + h * 128;
    for (int d = 0; d < 8; ++d)
      for (int r = 0; r < 4; ++r)
        O[obase + (size_t)(quad * 4 + r) * 2048 + d * 16 + l] = f2bf(Oacc[d][r] * inv[r]);
  }
}

// ---------------------------------------------------------------------------
extern "C" void kernel_launch(void* const* d_in, const int* in_sizes, int n_in,
                              void* d_out, int out_size, void* d_ws, size_t ws_size,
                              hipStream_t stream) {
  const void* X  = d_in[0];
  const void* Wq = d_in[3];
  const void* Wk = d_in[4];
  const void* Wv = d_in[5];
  const void* Wo = d_in[6];

  u16* base = (u16*)d_ws;
  int* flag = (int*)d_ws;
  const size_t TOK = 4096, DM = 2048;
  u16* Xbf = base + 128;               // 8M u16
  u16* Qw  = Xbf + TOK * DM;           // 8M
  u16* Kw  = Qw + TOK * DM;            // 8M
  u16* Vw  = Kw + TOK * DM;            // 8M (V, then attention output)
  u16* WT3 = Vw + TOK * DM;            // 12M u16: WqT ++ WkT ++ WvT (6144x2048)
  u16* Vtw = Xbf;                      // X dead after QKV gemm
  float* Wf = (float*)Xbf;             // f32 Wo-GEMM out: 33.5MB over Xbf+Qw+
                                       // head of Kw (all dead at Wo time)

  sniff_dtype<<<1, 256, 0, stream>>>((const unsigned*)X, flag);
  convert_x<<<4096, 256, 0, stream>>>(X, Xbf, flag);

  transpose_w3<<<dim3(32, 32, 3), 256, 0, stream>>>(Wq, Wk, Wv, WT3, flag);
  qkv_gemm<<<dim3(48, 32), 256, 0, stream>>>(Xbf, WT3, Qw, Kw, Vw);

  // rope(Q,K) + transpose_v + transpose_w(Wo) fused: all independent,
  // WT3 dead after qkv_gemm, Xbf (->Vtw) dead after qkv_gemm.
  mid_fused<<<4096, 256, 0, stream>>>(Qw, Kw, Vw, Vtw, Wo, WT3, flag);

  flash_k<<<dim3(16, 16, 2), 256, 0, stream>>>(Qw, Kw, Vtw, Vw);

  gemm128_wo<<<dim3(16, 32), 256, 0, stream>>>(Vw, WT3, Wf);
  convert_out<<<8192, 256, 0, stream>>>(Wf, d_out, flag);
}